// Round 9
// baseline (443.839 us; speedup 1.0000x reference)
//
#include <hip/hip_runtime.h>

typedef unsigned short u16;
typedef unsigned int   u32;

#define LOG2E 1.44269504088896340736f

// ---------------- dims ----------------
#define BT_TOT   8192      // B*T
#define SEQ      4096
#define DMODEL   1024
#define DINNER   2048
#define NHEADS   32
#define HEADDIM  64
#define DSTATE   128
#define CONVDIM  2304
#define DINPROJ  4384
#define NCHUNK   32        // per batch
#define CHUNKQ   128

typedef float  f32x4  __attribute__((ext_vector_type(4)));
typedef __bf16 bf16x8 __attribute__((ext_vector_type(8)));

// XOR swizzle of a byte offset within a 256B (or 128B) row
#define SWB(r, b) ((b) ^ (((r) & 7) << 4))

__device__ __forceinline__ u16 f2bf(float f) {
  u32 u = __float_as_uint(f);
  u += 0x7fffu + ((u >> 16) & 1u);
  return (u16)(u >> 16);
}
__device__ __forceinline__ float bf2f(u16 s) {
  return __uint_as_float(((u32)s) << 16);
}

// async global->LDS, 16B per lane; lds dest must be wave-uniform base (+lane*16 implicit)
__device__ __forceinline__ void async_cp16(const void* g, void* l) {
  __builtin_amdgcn_global_load_lds((const __attribute__((address_space(1))) u32*)g,
                                   (__attribute__((address_space(3))) u32*)l, 16, 0, 0);
}

template<int N> __device__ __forceinline__ void waitvm() {
  if constexpr (N == 0)      asm volatile("s_waitcnt vmcnt(0)" ::: "memory");
  else if constexpr (N == 3) asm volatile("s_waitcnt vmcnt(3)" ::: "memory");
  else if constexpr (N == 4) asm volatile("s_waitcnt vmcnt(4)" ::: "memory");
  else if constexpr (N == 6) asm volatile("s_waitcnt vmcnt(6)" ::: "memory");
  else if constexpr (N == 8) asm volatile("s_waitcnt vmcnt(8)" ::: "memory");
}

union bfpack { u16 u[8]; bf16x8 v; };

// ---------------- cast f32 -> bf16 (8 elems/thread) ----------------
__global__ __launch_bounds__(256) void cast_bf16(const float* __restrict__ in,
                                                 u16* __restrict__ out, int n8) {
  int i = blockIdx.x * 256 + threadIdx.x;
  if (i >= n8) return;
  const float4* p = (const float4*)in + (size_t)i * 2;
  float4 a = p[0], b = p[1];
  uint4 o;
  o.x = (u32)f2bf(a.x) | ((u32)f2bf(a.y) << 16);
  o.y = (u32)f2bf(a.z) | ((u32)f2bf(a.w) << 16);
  o.z = (u32)f2bf(b.x) | ((u32)f2bf(b.y) << 16);
  o.w = (u32)f2bf(b.z) | ((u32)f2bf(b.w) << 16);
  ((uint4*)out)[i] = o;
}

// ---------------- transpose + cast: in (R,C) f32 -> out (C,R) bf16 ----------------
__global__ __launch_bounds__(256) void tcast(const float* __restrict__ in,
                                             u16* __restrict__ out, int R, int C) {
  __shared__ float tile[32][33];
  int c0 = blockIdx.x * 32, r0 = blockIdx.y * 32;
  int tx = threadIdx.x & 31, ty = threadIdx.x >> 5;  // ty 0..7
  for (int dy = 0; dy < 32; dy += 8)
    tile[ty + dy][tx] = in[(size_t)(r0 + ty + dy) * C + c0 + tx];
  __syncthreads();
  for (int dy = 0; dy < 32; dy += 8)
    out[(size_t)(c0 + ty + dy) * R + r0 + tx] = f2bf(tile[tx][ty + dy]);
}

// ================= deep-pipelined GEMM (3-stage, BK=32, counted vmcnt) =================
// C(MxN) = A(MxK bf16) * Bt(NxK bf16)^T.  512 threads = 8 waves (WMW x WNW).
// 3 LDS buffers; tile t prefetched 2 K-tiles ahead; vmcnt(2V) steady state (never 0).
// LDS row = 64 B (4 x 16B slots), slot swizzle: slot ^= (row>>1)&3 -> conflict-free frags.
// MODE 1: bf16 output split to zb/xbcb via LDS-staged coalesced stores (BN=256 only).
// MODE 0: f32 direct output to Cf (N = Nn).
// NOTE: min-waves/EU arg must be 1: acc[MI][NI] alone is up to 128 VGPRs; the
// (512,2) variant capped VGPR at 128 and spilled the whole fragment set (r8).
template<int BM, int BN, int WMW, int WNW, int MODE>
__global__ __launch_bounds__(512, 1) void gemm_pipe(const u16* __restrict__ A,
                                                    const u16* __restrict__ Bt,
                                                    float* __restrict__ Cf,
                                                    u16* __restrict__ zb,
                                                    u16* __restrict__ xbcb,
                                                    int Nn, int K) {
  constexpr int MI   = BM / (WMW * 16);
  constexpr int NI   = BN / (WNW * 16);
  constexpr int LA   = BM / 128;          // gload_lds instrs per tile for A
  constexpr int LB   = BN / 128;
  constexpr int V    = LA + LB;           // loads per K-tile per wave
  constexpr int BUFU = (BM + BN) * 32;    // u16 per buffer
  __shared__ u16 sh[3 * BUFU];

  const int tid = threadIdx.x, lane = tid & 63, wave = tid >> 6;
  const int wm = wave / WNW, wn = wave % WNW;
  const int wm_w = wm * (BM / WMW), wn_w = wn * (BN / WNW);

  // XCD-aware bijective swizzle (grid sizes chosen %8==0)
  int flat = blockIdx.y * gridDim.x + blockIdx.x;
  int cpx  = (gridDim.x * gridDim.y) >> 3;
  int swz  = (flat & 7) * cpx + (flat >> 3);
  const int m0 = (swz / gridDim.x) * BM;
  const int n0 = (swz % gridDim.x) * BN;

  f32x4 acc[MI][NI] = {};

  auto issue = [&](int t) {
    const int bo = (t % 3) * BUFU;
    const int k0 = t * 32;
#pragma unroll
    for (int s = 0; s < LA; ++s) {
      int idx = s * 512 + tid;
      int row = idx >> 2, slot = idx & 3;
      int swo = (slot * 8) ^ (((row >> 1) & 3) << 3);   // u16 units
      async_cp16(A + (size_t)(m0 + row) * K + k0 + swo,
                 sh + bo + (s * 512 + wave * 64) * 8);
    }
#pragma unroll
    for (int s = 0; s < LB; ++s) {
      int idx = s * 512 + tid;
      int row = idx >> 2, slot = idx & 3;
      int swo = (slot * 8) ^ (((row >> 1) & 3) << 3);
      async_cp16(Bt + (size_t)(n0 + row) * K + k0 + swo,
                 sh + bo + BM * 32 + (s * 512 + wave * 64) * 8);
    }
  };

  const int T = K / 32;
  issue(0);
  issue(1);
  for (int t = 0; t < T; ++t) {
    if (t + 2 < T) {
      issue(t + 2);
      waitvm<2 * V>();       // retire tile t's loads; t+1,t+2 stay in flight
    } else if (t + 2 == T) {
      waitvm<V>();
    } else {
      waitvm<0>();
    }
    __syncthreads();
    const char* bA = (const char*)(sh + (t % 3) * BUFU);
    const char* bB = bA + BM * 64;
    bf16x8 a[MI], b[NI];
#pragma unroll
    for (int mi = 0; mi < MI; ++mi) {
      int r = wm_w + mi * 16 + (lane & 15);
      a[mi] = *(const bf16x8*)(bA + r * 64 + (((lane >> 4) << 4) ^ (((r >> 1) & 3) << 4)));
    }
#pragma unroll
    for (int ni = 0; ni < NI; ++ni) {
      int rn = wn_w + ni * 16 + (lane & 15);
      b[ni] = *(const bf16x8*)(bB + rn * 64 + (((lane >> 4) << 4) ^ (((rn >> 1) & 3) << 4)));
    }
#pragma unroll
    for (int mi = 0; mi < MI; ++mi)
#pragma unroll
      for (int ni = 0; ni < NI; ++ni)
        acc[mi][ni] = __builtin_amdgcn_mfma_f32_16x16x32_bf16(a[mi], b[ni], acc[mi][ni], 0, 0, 0);
    __syncthreads();
  }

  if constexpr (MODE == 1) {
    // bf16 split output via LDS staging (BN == 256): rows in WMW rounds of BM/WMW
    constexpr int ROWS = BM / WMW;
#pragma unroll
    for (int mh = 0; mh < WMW; ++mh) {
      if (wm == mh) {
#pragma unroll
        for (int mi = 0; mi < MI; ++mi)
#pragma unroll
          for (int ni = 0; ni < NI; ++ni) {
            int rr = mi * 16 + ((lane >> 4) << 2);
            int c  = wn_w + ni * 16 + (lane & 15);
#pragma unroll
            for (int j = 0; j < 4; ++j)
              *(u16*)((char*)sh + (rr + j) * (BN * 2) + ((2 * c) ^ (((rr + j) & 7) << 4))) =
                  f2bf(acc[mi][ni][j]);
          }
      }
      __syncthreads();
      u16* dst; int ldst, n0c;
      if (n0 < DINNER) { dst = zb;   ldst = DINNER;  n0c = n0; }
      else             { dst = xbcb; ldst = CONVDIM; n0c = n0 - DINNER; }
#pragma unroll
      for (int s = 0; s < ROWS * (BN / 8) / 512; ++s) {
        int idx = s * 512 + tid;
        int r2 = idx / (BN / 8), c16 = idx % (BN / 8);
        uint4 v = *(const uint4*)((char*)sh + r2 * (BN * 2) + ((c16 * 16) ^ ((r2 & 7) << 4)));
        *(uint4*)(dst + (size_t)(m0 + mh * ROWS + r2) * ldst + n0c + c16 * 8) = v;
      }
      __syncthreads();
    }
  } else {
    // f32 direct output
#pragma unroll
    for (int mi = 0; mi < MI; ++mi)
#pragma unroll
      for (int ni = 0; ni < NI; ++ni) {
        int r0 = m0 + wm_w + mi * 16 + ((lane >> 4) << 2);
        int c  = n0 + wn_w + ni * 16 + (lane & 15);
#pragma unroll
        for (int j = 0; j < 4; ++j)
          Cf[(size_t)(r0 + j) * Nn + c] = acc[mi][ni][j];
      }
  }
}

// ---- dt tail: columns 4352..4383 of x@Win^T, softplus(.+bias) -> dtb (f32) ----
// old proven 128x128 2-phase structure, grid = 64 m-blocks
__global__ __launch_bounds__(256) void gemm_dt(const u16* __restrict__ A,
                                               const u16* __restrict__ Bt,
                                               const float* __restrict__ dt_bias,
                                               float* __restrict__ dtb) {
  const int K = DMODEL, Nn = DINPROJ;
  __shared__ u16 sh[32768];
  const int tid = threadIdx.x, lane = tid & 63, wave = tid >> 6;
  const int wm = (wave >> 1) << 6, wn = (wave & 1) << 6;
  const int m0 = blockIdx.x * 128;
  const int n0 = 4352;

  f32x4 acc[4][4] = {};
  auto issue = [&](int buf, int k0) {
#pragma unroll
    for (int s = 0; s < 4; ++s) {
      int idx = s * 256 + tid;
      int row = idx >> 3, k16 = idx & 7;
      int swo = (k16 * 8) ^ ((row & 7) << 3);
      int lofs = (s * 256 + wave * 64) * 8;
      async_cp16(A + (size_t)(m0 + row) * K + k0 + swo, sh + buf * 16384 + lofs);
      int rn = n0 + row; if (rn > Nn - 1) rn = Nn - 1;
      async_cp16(Bt + (size_t)rn * K + k0 + swo, sh + buf * 16384 + 8192 + lofs);
    }
  };
  issue(0, 0);
  const int nk = K / 64;
  for (int kt = 0; kt < nk; ++kt) {
    int buf = kt & 1;
    asm volatile("s_waitcnt vmcnt(0)" ::: "memory");
    __syncthreads();
    if (kt + 1 < nk) issue(buf ^ 1, (kt + 1) * 64);
    const char* As = (const char*)(sh + buf * 16384);
    const char* Bs = (const char*)(sh + buf * 16384 + 8192);
#pragma unroll
    for (int ks = 0; ks < 2; ++ks) {
      bf16x8 af[4], bfr[4];
#pragma unroll
      for (int t = 0; t < 4; ++t) {
        int r  = wm + t * 16 + (lane & 15);
        int kb = ks * 64 + ((lane >> 4) << 4);
        af[t]  = *(const bf16x8*)(As + r * 128 + SWB(r, kb));
        int rn = wn + t * 16 + (lane & 15);
        bfr[t] = *(const bf16x8*)(Bs + rn * 128 + SWB(rn, kb));
      }
#pragma unroll
      for (int mi = 0; mi < 4; ++mi)
#pragma unroll
        for (int ni = 0; ni < 4; ++ni)
          acc[mi][ni] = __builtin_amdgcn_mfma_f32_16x16x32_bf16(af[mi], bfr[ni], acc[mi][ni], 0, 0, 0);
    }
  }
#pragma unroll
  for (int mi = 0; mi < 4; ++mi) {
#pragma unroll
    for (int ni = 0; ni < 4; ++ni) {
      int r0 = m0 + wm + mi * 16 + ((lane >> 4) << 2);
      int c  = n0 + wn + ni * 16 + (lane & 15);
      if (c < DINPROJ) {
        int h = c - 4352;
        float bias = dt_bias[h];
#pragma unroll
        for (int j = 0; j < 4; ++j) {
          float v = acc[mi][ni][j] + bias;
          dtb[(size_t)(r0 + j) * NHEADS + h] = (v > 20.f) ? v : log1pf(__expf(v));
        }
      }
    }
  }
}

// ---------------- depthwise causal conv1d + bias + silu (bf16 in/out) ----------------
__global__ __launch_bounds__(256) void conv_silu(const u16* __restrict__ xbcb,
                                                 const float* __restrict__ cw,
                                                 const float* __restrict__ cb,
                                                 u16* __restrict__ convb) {
  int c = blockIdx.x * 256 + threadIdx.x;  // 0..2303
  size_t bt = blockIdx.y;                  // 0..8191
  int t = (int)(bt & (SEQ - 1));
  float acc = cb[c];
#pragma unroll
  for (int k = 0; k < 4; ++k) {
    int tt = t - 3 + k;
    if (tt >= 0)
      acc = fmaf(bf2f(xbcb[(bt - 3 + (size_t)k) * CONVDIM + c]), cw[c * 4 + k], acc);
  }
  float s = acc / (1.f + __expf(-acc));
  convb[bt * CONVDIM + c] = f2bf(s);
}

// ---------------- per-(b,c,h) cumsum of dA over chunk; stores LOG2-domain ----------------
__global__ __launch_bounds__(128) void ssd_cumsum(const float* __restrict__ dtb,
                                                  const float* __restrict__ A_log,
                                                  float* __restrict__ dacs) {
  int bch = blockIdx.x;          // (b*32+c)*32+h
  int h = bch & 31, bc = bch >> 5;
  int q = threadIdx.x;
  float A = -__expf(A_log[h]);
  float v = dtb[((size_t)bc * 128 + q) * 32 + h] * A;
#pragma unroll
  for (int o = 1; o < 64; o <<= 1) {
    float u = __shfl_up(v, o, 64);
    if ((q & 63) >= o) v += u;
  }
  __shared__ float w0;
  if (q == 63) w0 = v;
  __syncthreads();
  if (q >= 64) v += w0;
  dacs[(size_t)bch * 128 + q] = v * LOG2E;
}

// ---------------- fused SSD intra per (b,c,h): G -> M -> Y_diag (+D*xh), S^T ----------------
__global__ __launch_bounds__(256) void ssd_intra2(const u16* __restrict__ convb,
                                                  const float* __restrict__ dacs,
                                                  const float* __restrict__ dtb,
                                                  const float* __restrict__ Dv,
                                                  float* __restrict__ y,
                                                  u16* __restrict__ S) {
  __shared__ u16 Cc[128 * 128];
  __shared__ u16 Bb[128 * 128];
  __shared__ u16 xhT[64 * 128];
  int bch = (blockIdx.x & 7) * 256 + (blockIdx.x >> 3);  // XCD swizzle (2048 %8==0)
  int h = bch & 31, bc = bch >> 5;
  size_t row0 = (size_t)bc * 128;
  int tid = threadIdx.x, lane = tid & 63, wave = tid >> 6;
  const float* cs = dacs + (size_t)bch * 128;   // log2-domain cumsum

  // ---- stage C,B (swizzled rows) and xh transposed ----
#pragma unroll
  for (int s = 0; s < 8; ++s) {
    int idx = s * 256 + tid;
    int r = idx >> 4, n16 = idx & 15;
    uint4 v = *(const uint4*)(convb + (row0 + r) * CONVDIM + (DINNER + DSTATE) + n16 * 8);
    *(uint4*)((char*)Cc + r * 256 + SWB(r, n16 * 16)) = v;
    uint4 w = *(const uint4*)(convb + (row0 + r) * CONVDIM + DINNER + n16 * 8);
    *(uint4*)((char*)Bb + r * 256 + SWB(r, n16 * 16)) = w;
  }
#pragma unroll
  for (int s = 0; s < 4; ++s) {
    int idx = s * 256 + tid;
    int q = idx >> 3, p0 = (idx & 7) * 8;
    uint4 v = *(const uint4*)(convb + (row0 + q) * CONVDIM + h * 64 + p0);
    const u16* e = (const u16*)&v;
#pragma unroll
    for (int k = 0; k < 8; ++k)
      *(u16*)((char*)xhT + (p0 + k) * 256 + SWB(p0 + k, 2 * q)) = e[k];
  }
  __syncthreads();

  // ---- G = C . B^T (k = n over 128): wave owns i rows [32w, 32w+32) ----
  f32x4 g[2][8] = {};
#pragma unroll
  for (int ks = 0; ks < 4; ++ks) {
    int kb = ks * 64 + ((lane >> 4) << 4);
    bf16x8 a[2], b[8];
#pragma unroll
    for (int fi = 0; fi < 2; ++fi) {
      int r = 32 * wave + fi * 16 + (lane & 15);
      a[fi] = *(const bf16x8*)((const char*)Cc + r * 256 + SWB(r, kb));
    }
#pragma unroll
    for (int fj = 0; fj < 8; ++fj) {
      int rj = fj * 16 + (lane & 15);
      b[fj] = *(const bf16x8*)((const char*)Bb + rj * 256 + SWB(rj, kb));
    }
#pragma unroll
    for (int fi = 0; fi < 2; ++fi)
#pragma unroll
      for (int fj = 0; fj < 8; ++fj)
        g[fi][fj] = __builtin_amdgcn_mfma_f32_16x16x32_bf16(a[fi], b[fj], g[fi][fj], 0, 0, 0);
  }

  // ---- build M (bf16) into Cc rows owned by this wave ----
#pragma unroll
  for (int fi = 0; fi < 2; ++fi) {
    int ib = 32 * wave + fi * 16 + ((lane >> 4) << 2);
    float ci[4];
#pragma unroll
    for (int r = 0; r < 4; ++r) ci[r] = cs[ib + r];
#pragma unroll
    for (int fj = 0; fj < 8; ++fj) {
      int j = fj * 16 + (lane & 15);
      float cj = cs[j];
      float dj = dtb[(row0 + j) * NHEADS + h];
#pragma unroll
      for (int r = 0; r < 4; ++r) {
        int i = ib + r;
        float m = (j <= i) ? g[fi][fj][r] * exp2f(ci[r] - cj) * dj : 0.f;
        *(u16*)((char*)Cc + i * 256 + SWB(i, 2 * j)) = f2bf(m);
      }
    }
  }

  // ---- Y_diag = M . xh (k = j), triangular k-skip; + D*xh; store y ----
  f32x4 yd[2][4] = {};
  for (int ks = 0; ks <= wave; ++ks) {
    int kb = ks * 64 + ((lane >> 4) << 4);
    bf16x8 a[2], b[4];
#pragma unroll
    for (int fi = 0; fi < 2; ++fi) {
      int r = 32 * wave + fi * 16 + (lane & 15);
      a[fi] = *(const bf16x8*)((const char*)Cc + r * 256 + SWB(r, kb));
    }
#pragma unroll
    for (int fp = 0; fp < 4; ++fp) {
      int pr = fp * 16 + (lane & 15);
      b[fp] = *(const bf16x8*)((const char*)xhT + pr * 256 + SWB(pr, kb));
    }
#pragma unroll
    for (int fi = 0; fi < 2; ++fi)
#pragma unroll
      for (int fp = 0; fp < 4; ++fp)
        yd[fi][fp] = __builtin_amdgcn_mfma_f32_16x16x32_bf16(a[fi], b[fp], yd[fi][fp], 0, 0, 0);
  }
  {
    float Dh = Dv[h];
#pragma unroll
    for (int fi = 0; fi < 2; ++fi) {
      int ib = 32 * wave + fi * 16 + ((lane >> 4) << 2);
#pragma unroll
      for (int fp = 0; fp < 4; ++fp) {
        int p = fp * 16 + (lane & 15);
#pragma unroll
        for (int r = 0; r < 4; ++r) {
          int i = ib + r;
          float xv = bf2f(*(const u16*)((const char*)xhT + p * 256 + SWB(p, 2 * i)));
          y[(row0 + i) * DINNER + h * 64 + p] = yd[fi][fp][r] + Dh * xv;
        }
      }
    }
  }

  // ---- S[n][p] = sum_q (B[q][n]*w_q) * xh[q][p] (k = q); wave owns n rows ----
  float cl = cs[127];
  f32x4 sa[2][4] = {};
#pragma unroll
  for (int ks = 0; ks < 4; ++ks) {
    int qb = ks * 32 + ((lane >> 4) << 3);
    float wv[8];
#pragma unroll
    for (int e = 0; e < 8; ++e)
      wv[e] = exp2f(cl - cs[qb + e]) * dtb[(row0 + qb + e) * NHEADS + h];
    bf16x8 a[2], b[4];
#pragma unroll
    for (int fn = 0; fn < 2; ++fn) {
      int n = 32 * wave + fn * 16 + (lane & 15);
      bfpack t;
#pragma unroll
      for (int e = 0; e < 8; ++e) {
        int q = qb + e;
        float bv = bf2f(*(const u16*)((const char*)Bb + q * 256 + SWB(q, 2 * n)));
        t.u[e] = f2bf(bv * wv[e]);
      }
      a[fn] = t.v;
    }
    int kb = ks * 64 + ((lane >> 4) << 4);
#pragma unroll
    for (int fp = 0; fp < 4; ++fp) {
      int pr = fp * 16 + (lane & 15);
      b[fp] = *(const bf16x8*)((const char*)xhT + pr * 256 + SWB(pr, kb));
    }
#pragma unroll
    for (int fn = 0; fn < 2; ++fn)
#pragma unroll
      for (int fp = 0; fp < 4; ++fp)
        sa[fn][fp] = __builtin_amdgcn_mfma_f32_16x16x32_bf16(a[fn], b[fp], sa[fn][fp], 0, 0, 0);
  }
  // stage S^T[p][n] into Cc region, then coalesced copy out
  __syncthreads();
#pragma unroll
  for (int fn = 0; fn < 2; ++fn) {
    int nb = 32 * wave + fn * 16 + ((lane >> 4) << 2);
#pragma unroll
    for (int fp = 0; fp < 4; ++fp) {
      int p = fp * 16 + (lane & 15);
#pragma unroll
      for (int r = 0; r < 4; ++r)
        *(u16*)((char*)Cc + p * 256 + SWB(p, 2 * (nb + r))) = f2bf(sa[fn][fp][r]);
    }
  }
  __syncthreads();
#pragma unroll
  for (int s = 0; s < 4; ++s) {
    int idx = s * 256 + tid;
    int p = idx >> 4, n16 = idx & 15;
    uint4 v = *(const uint4*)((char*)Cc + p * 256 + SWB(p, n16 * 16));
    *(uint4*)(S + (size_t)bch * 8192 + p * 128 + n16 * 8) = v;
  }
}

// ---------------- inter-chunk scan (in place; S layout [p][n] flat 8192/bch) -------
__global__ __launch_bounds__(256) void ssd_scan(u16* __restrict__ S,
                                                const float* __restrict__ dacs) {
  int f = blockIdx.x * 256 + threadIdx.x;   // 524288 total
  int e = f & 8191;
  int bh = f >> 13;
  int b = bh >> 5, h = bh & 31;
  float carry = 0.f;
  for (int c = 0; c < NCHUNK; ++c) {
    size_t bch = ((size_t)b * 32 + c) * 32 + h;
    size_t off = bch * 8192 + e;
    float s = bf2f(S[off]);
    S[off] = f2bf(carry);
    float cd = exp2f(dacs[bch * 128 + 127]);
    carry = fmaf(carry, cd, s);
  }
}

// ---------------- Y_off: y += exp2(cs_i) * C(128x128) . prev^T-layout (MFMA) ----------------
__global__ __launch_bounds__(256) void ssd_off2(const u16* __restrict__ convb,
                                                const u16* __restrict__ S,
                                                const float* __restrict__ dacs,
                                                float* __restrict__ y) {
  __shared__ u16 Cc[128 * 128];
  __shared__ u16 pv[64 * 128];   // prev as [p][n]
  int bch = (blockIdx.x & 7) * 256 + (blockIdx.x >> 3);
  int h = bch & 31, bc = bch >> 5;
  size_t row0 = (size_t)bc * 128;
  int tid = threadIdx.x, lane = tid & 63, wave = tid >> 6;
  const float* cs = dacs + (size_t)bch * 128;

#pragma unroll
  for (int s = 0; s < 8; ++s) {
    int idx = s * 256 + tid;
    int r = idx >> 4, n16 = idx & 15;
    uint4 v = *(const uint4*)(convb + (row0 + r) * CONVDIM + (DINNER + DSTATE) + n16 * 8);
    *(uint4*)((char*)Cc + r * 256 + SWB(r, n16 * 16)) = v;
  }
#pragma unroll
  for (int s = 0; s < 4; ++s) {
    int idx = s * 256 + tid;
    int p = idx >> 4, n16 = idx & 15;
    uint4 v = *(const uint4*)(S + (size_t)bch * 8192 + p * 128 + n16 * 8);
    *(uint4*)((char*)pv + p * 256 + SWB(p, n16 * 16)) = v;
  }
  __syncthreads();

  f32x4 acc[2][4] = {};
#pragma unroll
  for (int ks = 0; ks < 4; ++ks) {
    int kb = ks * 64 + ((lane >> 4) << 4);
    bf16x8 a[2], b[4];
#pragma unroll
    for (int fi = 0; fi < 2; ++fi) {
      int r = 32 * wave + fi * 16 + (lane & 15);
      a[fi] = *(const bf16x8*)((const char*)Cc + r * 256 + SWB(r, kb));
    }
#pragma unroll
    for (int fp = 0; fp < 4; ++fp) {
      int pr = fp * 16 + (lane & 15);
      b[fp] = *(const bf16x8*)((const char*)pv + pr * 256 + SWB(pr, kb));
    }
#pragma unroll
    for (int fi = 0; fi < 2; ++fi)
#pragma unroll
      for (int fp = 0; fp < 4; ++fp)
        acc[fi][fp] = __builtin_amdgcn_mfma_f32_16x16x32_bf16(a[fi], b[fp], acc[fi][fp], 0, 0, 0);
  }
#pragma unroll
  for (int fi = 0; fi < 2; ++fi) {
    int ib = 32 * wave + fi * 16 + ((lane >> 4) << 2);
    float ei[4];
#pragma unroll
    for (int r = 0; r < 4; ++r) ei[r] = exp2f(cs[ib + r]);
#pragma unroll
    for (int fp = 0; fp < 4; ++fp) {
      int p = fp * 16 + (lane & 15);
#pragma unroll
      for (int r = 0; r < 4; ++r) {
        float* yp = &y[(row0 + ib + r) * DINNER + h * 64 + p];
        *yp = fmaf(ei[r], acc[fi][fp][r], *yp);
      }
    }
  }
}

// ---------------- gated RMSNorm -> bf16 ----------------
__global__ __launch_bounds__(256) void gated_norm(const float* __restrict__ y,
                                                  const u16* __restrict__ zb,
                                                  const float* __restrict__ normw,
                                                  u16* __restrict__ yb) {
  size_t bt = blockIdx.x;
  int tid = threadIdx.x;
  const float* yr = y + bt * DINNER;
  const u16* zr = zb + bt * DINNER;
  float g[8];
  float ss = 0.f;
#pragma unroll
  for (int s = 0; s < 8; ++s) {
    int c = tid + s * 256;
    float z = bf2f(zr[c]);
    float v = yr[c] * (z / (1.f + __expf(-z)));
    g[s] = v;
    ss = fmaf(v, v, ss);
  }
#pragma unroll
  for (int o = 1; o < 64; o <<= 1) ss += __shfl_xor(ss, o, 64);
  __shared__ float red[4];
  if ((tid & 63) == 0) red[tid >> 6] = ss;
  __syncthreads();
  float tot = red[0] + red[1] + red[2] + red[3];
  float r = rsqrtf(tot * (1.f / (float)DINNER) + 1e-5f);
#pragma unroll
  for (int s = 0; s < 8; ++s) {
    int c = tid + s * 256;
    yb[bt * DINNER + c] = f2bf(g[s] * r * normw[c]);
  }
}

// ---------------- workspace layout (~231 MiB) ----------------
constexpr size_t SZ_XB   = (size_t)BT_TOT * DMODEL * 2;
constexpr size_t SZ_WIB  = (size_t)DINPROJ * DMODEL * 2;
constexpr size_t SZ_WOB  = (size_t)DMODEL * DINNER * 2;
constexpr size_t SZ_ZB   = (size_t)BT_TOT * DINNER * 2;
constexpr size_t SZ_XBCB = (size_t)BT_TOT * CONVDIM * 2;   // reused by yb
constexpr size_t SZ_DTB  = (size_t)BT_TOT * NHEADS * 4;
constexpr size_t SZ_DACS = (size_t)2048 * 128 * 4;
constexpr size_t SZ_CONV = (size_t)BT_TOT * CONVDIM * 2;
constexpr size_t SZ_SB   = (size_t)2048 * 128 * 64 * 2;
constexpr size_t SZ_Y    = (size_t)BT_TOT * DINNER * 4;

constexpr size_t OFF_XB   = 0;
constexpr size_t OFF_WIB  = OFF_XB + SZ_XB;
constexpr size_t OFF_WOB  = OFF_WIB + SZ_WIB;
constexpr size_t OFF_ZB   = OFF_WOB + SZ_WOB;
constexpr size_t OFF_XBCB = OFF_ZB + SZ_ZB;
constexpr size_t OFF_DTB  = OFF_XBCB + SZ_XBCB;
constexpr size_t OFF_DACS = OFF_DTB + SZ_DTB;
constexpr size_t OFF_CONV = OFF_DACS + SZ_DACS;
constexpr size_t OFF_SB   = OFF_CONV + SZ_CONV;
constexpr size_t OFF_Y    = OFF_SB + SZ_SB;
constexpr size_t WS_NEEDED = OFF_Y + SZ_Y;

extern "C" void kernel_launch(void* const* d_in, const int* in_sizes, int n_in,
                              void* d_out, int out_size, void* d_ws, size_t ws_size,
                              hipStream_t stream) {
  (void)in_sizes; (void)n_in; (void)out_size;
  if (ws_size < WS_NEEDED) return;

  const float* x      = (const float*)d_in[0];
  const float* Win    = (const float*)d_in[1];
  const float* cw     = (const float*)d_in[2];
  const float* cb     = (const float*)d_in[3];
  const float* dtbias = (const float*)d_in[4];
  const float* A_log  = (const float*)d_in[5];
  const float* Dv     = (const float*)d_in[6];
  const float* normw  = (const float*)d_in[7];
  const float* Wout   = (const float*)d_in[8];
  float* out = (float*)d_out;

  char* ws = (char*)d_ws;
  u16*   xb    = (u16*)  (ws + OFF_XB);
  u16*   wib   = (u16*)  (ws + OFF_WIB);
  u16*   wob   = (u16*)  (ws + OFF_WOB);
  u16*   zb    = (u16*)  (ws + OFF_ZB);
  u16*   xbcb  = (u16*)  (ws + OFF_XBCB);
  float* dtb   = (float*)(ws + OFF_DTB);
  float* dacs  = (float*)(ws + OFF_DACS);
  u16*   convb = (u16*)  (ws + OFF_CONV);
  u16*   sb    = (u16*)  (ws + OFF_SB);
  float* y     = (float*)(ws + OFF_Y);
  u16*   yb    = (u16*)  (ws + OFF_XBCB);  // overlay: xbcb dead after conv_silu

  cast_bf16<<<dim3(4096), dim3(256), 0, stream>>>(x, xb, BT_TOT * DMODEL / 8);
  tcast<<<dim3(DINPROJ / 32, DMODEL / 32), dim3(256), 0, stream>>>(Win, wib, DMODEL, DINPROJ);
  tcast<<<dim3(DMODEL / 32, DINNER / 32), dim3(256), 0, stream>>>(Wout, wob, DINNER, DMODEL);

  // main in-proj: cols 0..4351 (z + xBC), 256x256 tiles, deep pipeline
  gemm_pipe<256, 256, 2, 4, 1><<<dim3(17, 32), dim3(512), 0, stream>>>(
      xb, wib, nullptr, zb, xbcb, DINPROJ, DMODEL);
  // dt tail: cols 4352..4383
  gemm_dt<<<dim3(64), dim3(256), 0, stream>>>(xb, wib, dtbias, dtb);

  conv_silu<<<dim3(CONVDIM / 256, BT_TOT), dim3(256), 0, stream>>>(xbcb, cw, cb, convb);
  ssd_cumsum<<<dim3(2048), dim3(128), 0, stream>>>(dtb, A_log, dacs);
  ssd_intra2<<<dim3(2048), dim3(256), 0, stream>>>(convb, dacs, dtb, Dv, y, sb);
  ssd_scan<<<dim3(2048), dim3(256), 0, stream>>>(sb, dacs);
  ssd_off2<<<dim3(2048), dim3(256), 0, stream>>>(convb, sb, dacs, y);
  gated_norm<<<dim3(BT_TOT), dim3(256), 0, stream>>>(y, zb, normw, yb);

  gemm_pipe<256, 128, 4, 2, 0><<<dim3(8, 32), dim3(512), 0, stream>>>(
      yb, wob, out, nullptr, nullptr, DMODEL, DINNER);
}

// Round 10
// 410.302 us; speedup vs baseline: 1.0817x; 1.0817x over previous
//
#include <hip/hip_runtime.h>

typedef unsigned short u16;
typedef unsigned int   u32;

#define LOG2E 1.44269504088896340736f

// ---------------- dims ----------------
#define BT_TOT   8192      // B*T
#define SEQ      4096
#define DMODEL   1024
#define DINNER   2048
#define NHEADS   32
#define HEADDIM  64
#define DSTATE   128
#define CONVDIM  2304
#define DINPROJ  4384
#define NCHUNK   32        // per batch
#define CHUNKQ   128

typedef float  f32x4  __attribute__((ext_vector_type(4)));
typedef __bf16 bf16x8 __attribute__((ext_vector_type(8)));

// XOR swizzle of a byte offset within a 256B (or 128B) row
#define SWB(r, b) ((b) ^ (((r) & 7) << 4))

__device__ __forceinline__ u16 f2bf(float f) {
  u32 u = __float_as_uint(f);
  u += 0x7fffu + ((u >> 16) & 1u);
  return (u16)(u >> 16);
}
__device__ __forceinline__ float bf2f(u16 s) {
  return __uint_as_float(((u32)s) << 16);
}

// async global->LDS, 16B per lane; lds dest must be wave-uniform base (+lane*16 implicit)
__device__ __forceinline__ void async_cp16(const void* g, void* l) {
  __builtin_amdgcn_global_load_lds((const __attribute__((address_space(1))) u32*)g,
                                   (__attribute__((address_space(3))) u32*)l, 16, 0, 0);
}

union bfpack { u16 u[8]; bf16x8 v; };

// ---------------- cast f32 -> bf16 (8 elems/thread) ----------------
__global__ __launch_bounds__(256) void cast_bf16(const float* __restrict__ in,
                                                 u16* __restrict__ out, int n8) {
  int i = blockIdx.x * 256 + threadIdx.x;
  if (i >= n8) return;
  const float4* p = (const float4*)in + (size_t)i * 2;
  float4 a = p[0], b = p[1];
  uint4 o;
  o.x = (u32)f2bf(a.x) | ((u32)f2bf(a.y) << 16);
  o.y = (u32)f2bf(a.z) | ((u32)f2bf(a.w) << 16);
  o.z = (u32)f2bf(b.x) | ((u32)f2bf(b.y) << 16);
  o.w = (u32)f2bf(b.z) | ((u32)f2bf(b.w) << 16);
  ((uint4*)out)[i] = o;
}

// ---------------- transpose + cast: in (R,C) f32 -> out (C,R) bf16 ----------------
__global__ __launch_bounds__(256) void tcast(const float* __restrict__ in,
                                             u16* __restrict__ out, int R, int C) {
  __shared__ float tile[32][33];
  int c0 = blockIdx.x * 32, r0 = blockIdx.y * 32;
  int tx = threadIdx.x & 31, ty = threadIdx.x >> 5;  // ty 0..7
  for (int dy = 0; dy < 32; dy += 8)
    tile[ty + dy][tx] = in[(size_t)(r0 + ty + dy) * C + c0 + tx];
  __syncthreads();
  for (int dy = 0; dy < 32; dy += 8)
    out[(size_t)(c0 + ty + dy) * R + r0 + tx] = f2bf(tile[tx][ty + dy]);
}

// ================= GEMM cores (round-4 proven: 128x128, BK=64, 2-phase, 64KB LDS,
//                  2 blocks/CU -> inter-block overlap hides the barrier drain) =====

// ---- GEMM1: zxbcdt = xb @ Win^T with split epilogue ----
__global__ __launch_bounds__(256) void gemm_in(const u16* __restrict__ A,
                                               const u16* __restrict__ Bt,
                                               const float* __restrict__ dt_bias,
                                               u16* __restrict__ zb,
                                               u16* __restrict__ xbcb,
                                               float* __restrict__ dtb) {
  const int K = DMODEL, Nn = DINPROJ;
  __shared__ u16 sh[32768];
  const int tid = threadIdx.x, lane = tid & 63, wave = tid >> 6;
  const int wm = (wave >> 1) << 6, wn = (wave & 1) << 6;
  // XCD swizzle (nwg = 35*64 = 2240, %8==0)
  int flat = blockIdx.y * gridDim.x + blockIdx.x;
  int cpx = (gridDim.x * gridDim.y) >> 3;
  int swz = (flat & 7) * cpx + (flat >> 3);
  const int m0 = (swz / gridDim.x) * 128;
  const int n0 = (swz % gridDim.x) * 128;

  f32x4 acc[4][4] = {};

  auto issue = [&](int buf, int k0) {
#pragma unroll
    for (int s = 0; s < 4; ++s) {
      int idx = s * 256 + tid;
      int row = idx >> 3, k16 = idx & 7;
      int swo = (k16 * 8) ^ ((row & 7) << 3);          // u16 units
      int lofs = (s * 256 + wave * 64) * 8;            // wave-uniform u16 offset
      async_cp16(A + (size_t)(m0 + row) * K + k0 + swo, sh + buf * 16384 + lofs);
      int rn = n0 + row; if (rn > Nn - 1) rn = Nn - 1;
      async_cp16(Bt + (size_t)rn * K + k0 + swo, sh + buf * 16384 + 8192 + lofs);
    }
  };
  issue(0, 0);
  const int nk = K / 64;
  for (int kt = 0; kt < nk; ++kt) {
    int buf = kt & 1;
    asm volatile("s_waitcnt vmcnt(0)" ::: "memory");
    __syncthreads();
    if (kt + 1 < nk) issue(buf ^ 1, (kt + 1) * 64);
    const char* As = (const char*)(sh + buf * 16384);
    const char* Bs = (const char*)(sh + buf * 16384 + 8192);
#pragma unroll
    for (int ks = 0; ks < 2; ++ks) {
      bf16x8 af[4], bfr[4];
#pragma unroll
      for (int t = 0; t < 4; ++t) {
        int r  = wm + t * 16 + (lane & 15);
        int kb = ks * 64 + ((lane >> 4) << 4);
        af[t]  = *(const bf16x8*)(As + r * 128 + SWB(r, kb));
        int rn = wn + t * 16 + (lane & 15);
        bfr[t] = *(const bf16x8*)(Bs + rn * 128 + SWB(rn, kb));
      }
#pragma unroll
      for (int mi = 0; mi < 4; ++mi)
#pragma unroll
        for (int ni = 0; ni < 4; ++ni)
          acc[mi][ni] = __builtin_amdgcn_mfma_f32_16x16x32_bf16(af[mi], bfr[ni], acc[mi][ni], 0, 0, 0);
    }
  }
  __syncthreads();
  if (n0 == 4352) {  // dt block: scalar softplus epilogue (only 32 valid cols)
#pragma unroll
    for (int mi = 0; mi < 4; ++mi) {
#pragma unroll
      for (int ni = 0; ni < 4; ++ni) {
        int r0 = m0 + wm + mi * 16 + ((lane >> 4) << 2);
        int c  = n0 + wn + ni * 16 + (lane & 15);
        if (c < DINPROJ) {
          int h = c - 4352;
          float bias = dt_bias[h];
#pragma unroll
          for (int j = 0; j < 4; ++j) {
            float v = acc[mi][ni][j] + bias;
            dtb[(size_t)(r0 + j) * NHEADS + h] = (v > 20.f) ? v : log1pf(__expf(v));
          }
        }
      }
    }
  } else {
    // stage bf16 tile into LDS, then coalesced uint4 writes
#pragma unroll
    for (int mi = 0; mi < 4; ++mi)
#pragma unroll
      for (int ni = 0; ni < 4; ++ni) {
        int il = wm + mi * 16 + ((lane >> 4) << 2);
        int cl = wn + ni * 16 + (lane & 15);
#pragma unroll
        for (int j = 0; j < 4; ++j)
          *(u16*)((char*)sh + (il + j) * 256 + SWB(il + j, 2 * cl)) = f2bf(acc[mi][ni][j]);
      }
    __syncthreads();
    u16* dst; int ldst, n0c;
    if (n0 < 2048) { dst = zb;   ldst = DINNER;  n0c = n0; }
    else           { dst = xbcb; ldst = CONVDIM; n0c = n0 - 2048; }
#pragma unroll
    for (int s = 0; s < 8; ++s) {   // 128 rows x 16 uint4 = 2048 = 8*256
      int idx = s * 256 + tid;
      int r = idx >> 4, n16 = idx & 15;
      uint4 v = *(const uint4*)((char*)sh + r * 256 + SWB(r, n16 * 16));
      *(uint4*)(dst + (size_t)(m0 + r) * ldst + n0c + n16 * 8) = v;
    }
  }
}

// ---- GEMM2: out = yb @ Wout^T, f32 output ----
__global__ __launch_bounds__(256) void gemm_out(const u16* __restrict__ A,
                                                const u16* __restrict__ Bt,
                                                float* __restrict__ C) {
  const int K = DINNER, Nn = DMODEL;
  __shared__ u16 sh[32768];
  const int tid = threadIdx.x, lane = tid & 63, wave = tid >> 6;
  const int wm = (wave >> 1) << 6, wn = (wave & 1) << 6;
  int flat = blockIdx.y * gridDim.x + blockIdx.x;   // nwg = 8*64 = 512
  int cpx = (gridDim.x * gridDim.y) >> 3;
  int swz = (flat & 7) * cpx + (flat >> 3);
  const int m0 = (swz / gridDim.x) * 128;
  const int n0 = (swz % gridDim.x) * 128;

  f32x4 acc[4][4] = {};
  auto issue = [&](int buf, int k0) {
#pragma unroll
    for (int s = 0; s < 4; ++s) {
      int idx = s * 256 + tid;
      int row = idx >> 3, k16 = idx & 7;
      int swo = (k16 * 8) ^ ((row & 7) << 3);
      int lofs = (s * 256 + wave * 64) * 8;
      async_cp16(A + (size_t)(m0 + row) * K + k0 + swo, sh + buf * 16384 + lofs);
      async_cp16(Bt + (size_t)(n0 + row) * K + k0 + swo, sh + buf * 16384 + 8192 + lofs);
    }
  };
  issue(0, 0);
  const int nk = K / 64;
  for (int kt = 0; kt < nk; ++kt) {
    int buf = kt & 1;
    asm volatile("s_waitcnt vmcnt(0)" ::: "memory");
    __syncthreads();
    if (kt + 1 < nk) issue(buf ^ 1, (kt + 1) * 64);
    const char* As = (const char*)(sh + buf * 16384);
    const char* Bs = (const char*)(sh + buf * 16384 + 8192);
#pragma unroll
    for (int ks = 0; ks < 2; ++ks) {
      bf16x8 af[4], bfr[4];
#pragma unroll
      for (int t = 0; t < 4; ++t) {
        int r  = wm + t * 16 + (lane & 15);
        int kb = ks * 64 + ((lane >> 4) << 4);
        af[t]  = *(const bf16x8*)(As + r * 128 + SWB(r, kb));
        int rn = wn + t * 16 + (lane & 15);
        bfr[t] = *(const bf16x8*)(Bs + rn * 128 + SWB(rn, kb));
      }
#pragma unroll
      for (int mi = 0; mi < 4; ++mi)
#pragma unroll
        for (int ni = 0; ni < 4; ++ni)
          acc[mi][ni] = __builtin_amdgcn_mfma_f32_16x16x32_bf16(af[mi], bfr[ni], acc[mi][ni], 0, 0, 0);
    }
  }
#pragma unroll
  for (int mi = 0; mi < 4; ++mi) {
#pragma unroll
    for (int ni = 0; ni < 4; ++ni) {
      int r0 = m0 + wm + mi * 16 + ((lane >> 4) << 2);
      int c  = n0 + wn + ni * 16 + (lane & 15);
#pragma unroll
      for (int j = 0; j < 4; ++j)
        C[(size_t)(r0 + j) * Nn + c] = acc[mi][ni][j];
    }
  }
}

// ---------------- depthwise causal conv1d + bias + silu (bf16, 8 ch/thread) ----------------
__global__ __launch_bounds__(256) void conv_silu(const u16* __restrict__ xbcb,
                                                 const float* __restrict__ cw,
                                                 const float* __restrict__ cb,
                                                 u16* __restrict__ convb) {
  int i = blockIdx.x * 256 + threadIdx.x;   // 8192 * 288
  int bt = i / 288, c8 = i - bt * 288;
  int c0 = c8 * 8;
  int t = bt & (SEQ - 1);
  float acc[8];
#pragma unroll
  for (int e = 0; e < 8; ++e) acc[e] = cb[c0 + e];
#pragma unroll
  for (int k = 0; k < 4; ++k) {
    int tt = t - 3 + k;
    if (tt >= 0) {
      uint4 v = *(const uint4*)(xbcb + (size_t)(bt - 3 + k) * CONVDIM + c0);
      const u16* e16 = (const u16*)&v;
#pragma unroll
      for (int e = 0; e < 8; ++e)
        acc[e] = fmaf(bf2f(e16[e]), cw[(c0 + e) * 4 + k], acc[e]);
    }
  }
  uint4 o;
  u16* o16 = (u16*)&o;
#pragma unroll
  for (int e = 0; e < 8; ++e) {
    float s = acc[e] / (1.f + __expf(-acc[e]));
    o16[e] = f2bf(s);
  }
  *(uint4*)(convb + (size_t)bt * CONVDIM + c0) = o;
}

// ---------------- per-(b,c,h) cumsum of dA over chunk; stores LOG2-domain ----------------
__global__ __launch_bounds__(128) void ssd_cumsum(const float* __restrict__ dtb,
                                                  const float* __restrict__ A_log,
                                                  float* __restrict__ dacs) {
  int bch = blockIdx.x;          // (b*32+c)*32+h
  int h = bch & 31, bc = bch >> 5;
  int q = threadIdx.x;
  float A = -__expf(A_log[h]);
  float v = dtb[((size_t)bc * 128 + q) * 32 + h] * A;
#pragma unroll
  for (int o = 1; o < 64; o <<= 1) {
    float u = __shfl_up(v, o, 64);
    if ((q & 63) >= o) v += u;
  }
  __shared__ float w0;
  if (q == 63) w0 = v;
  __syncthreads();
  if (q >= 64) v += w0;
  dacs[(size_t)bch * 128 + q] = v * LOG2E;
}

// ---------------- fused SSD intra per (b,c,h): G -> M -> Y_diag (+D*xh), S^T ----------------
__global__ __launch_bounds__(256) void ssd_intra2(const u16* __restrict__ convb,
                                                  const float* __restrict__ dacs,
                                                  const float* __restrict__ dtb,
                                                  const float* __restrict__ Dv,
                                                  u16* __restrict__ y,
                                                  u16* __restrict__ S) {
  __shared__ u16 Cc[128 * 128];
  __shared__ u16 Bb[128 * 128];
  __shared__ u16 xhT[64 * 128];
  int bch = (blockIdx.x & 7) * 256 + (blockIdx.x >> 3);  // XCD swizzle (2048 %8==0)
  int h = bch & 31, bc = bch >> 5;
  size_t row0 = (size_t)bc * 128;
  int tid = threadIdx.x, lane = tid & 63, wave = tid >> 6;
  const float* cs = dacs + (size_t)bch * 128;   // log2-domain cumsum

  // ---- stage C,B (swizzled rows) and xh transposed ----
#pragma unroll
  for (int s = 0; s < 8; ++s) {
    int idx = s * 256 + tid;
    int r = idx >> 4, n16 = idx & 15;
    uint4 v = *(const uint4*)(convb + (row0 + r) * CONVDIM + (DINNER + DSTATE) + n16 * 8);
    *(uint4*)((char*)Cc + r * 256 + SWB(r, n16 * 16)) = v;
    uint4 w = *(const uint4*)(convb + (row0 + r) * CONVDIM + DINNER + n16 * 8);
    *(uint4*)((char*)Bb + r * 256 + SWB(r, n16 * 16)) = w;
  }
#pragma unroll
  for (int s = 0; s < 4; ++s) {
    int idx = s * 256 + tid;
    int q = idx >> 3, p0 = (idx & 7) * 8;
    uint4 v = *(const uint4*)(convb + (row0 + q) * CONVDIM + h * 64 + p0);
    const u16* e = (const u16*)&v;
#pragma unroll
    for (int k = 0; k < 8; ++k)
      *(u16*)((char*)xhT + (p0 + k) * 256 + SWB(p0 + k, 2 * q)) = e[k];
  }
  __syncthreads();

  // ---- G = C . B^T (k = n over 128): wave owns i rows [32w, 32w+32) ----
  f32x4 g[2][8] = {};
#pragma unroll
  for (int ks = 0; ks < 4; ++ks) {
    int kb = ks * 64 + ((lane >> 4) << 4);
    bf16x8 a[2], b[8];
#pragma unroll
    for (int fi = 0; fi < 2; ++fi) {
      int r = 32 * wave + fi * 16 + (lane & 15);
      a[fi] = *(const bf16x8*)((const char*)Cc + r * 256 + SWB(r, kb));
    }
#pragma unroll
    for (int fj = 0; fj < 8; ++fj) {
      int rj = fj * 16 + (lane & 15);
      b[fj] = *(const bf16x8*)((const char*)Bb + rj * 256 + SWB(rj, kb));
    }
#pragma unroll
    for (int fi = 0; fi < 2; ++fi)
#pragma unroll
      for (int fj = 0; fj < 8; ++fj)
        g[fi][fj] = __builtin_amdgcn_mfma_f32_16x16x32_bf16(a[fi], b[fj], g[fi][fj], 0, 0, 0);
  }

  // ---- build M (bf16) into Cc rows owned by this wave ----
#pragma unroll
  for (int fi = 0; fi < 2; ++fi) {
    int ib = 32 * wave + fi * 16 + ((lane >> 4) << 2);
    float ci[4];
#pragma unroll
    for (int r = 0; r < 4; ++r) ci[r] = cs[ib + r];
#pragma unroll
    for (int fj = 0; fj < 8; ++fj) {
      int j = fj * 16 + (lane & 15);
      float cj = cs[j];
      float dj = dtb[(row0 + j) * NHEADS + h];
#pragma unroll
      for (int r = 0; r < 4; ++r) {
        int i = ib + r;
        float m = (j <= i) ? g[fi][fj][r] * exp2f(ci[r] - cj) * dj : 0.f;
        *(u16*)((char*)Cc + i * 256 + SWB(i, 2 * j)) = f2bf(m);
      }
    }
  }

  // ---- Y_diag = M . xh (k = j), triangular k-skip; + D*xh; store y (bf16) ----
  f32x4 yd[2][4] = {};
  for (int ks = 0; ks <= wave; ++ks) {
    int kb = ks * 64 + ((lane >> 4) << 4);
    bf16x8 a[2], b[4];
#pragma unroll
    for (int fi = 0; fi < 2; ++fi) {
      int r = 32 * wave + fi * 16 + (lane & 15);
      a[fi] = *(const bf16x8*)((const char*)Cc + r * 256 + SWB(r, kb));
    }
#pragma unroll
    for (int fp = 0; fp < 4; ++fp) {
      int pr = fp * 16 + (lane & 15);
      b[fp] = *(const bf16x8*)((const char*)xhT + pr * 256 + SWB(pr, kb));
    }
#pragma unroll
    for (int fi = 0; fi < 2; ++fi)
#pragma unroll
      for (int fp = 0; fp < 4; ++fp)
        yd[fi][fp] = __builtin_amdgcn_mfma_f32_16x16x32_bf16(a[fi], b[fp], yd[fi][fp], 0, 0, 0);
  }
  {
    float Dh = Dv[h];
#pragma unroll
    for (int fi = 0; fi < 2; ++fi) {
      int ib = 32 * wave + fi * 16 + ((lane >> 4) << 2);
#pragma unroll
      for (int fp = 0; fp < 4; ++fp) {
        int p = fp * 16 + (lane & 15);
#pragma unroll
        for (int r = 0; r < 4; ++r) {
          int i = ib + r;
          float xv = bf2f(*(const u16*)((const char*)xhT + p * 256 + SWB(p, 2 * i)));
          y[(row0 + i) * DINNER + h * 64 + p] = f2bf(yd[fi][fp][r] + Dh * xv);
        }
      }
    }
  }

  // ---- S[n][p] = sum_q (B[q][n]*w_q) * xh[q][p] (k = q); wave owns n rows ----
  float cl = cs[127];
  f32x4 sa[2][4] = {};
#pragma unroll
  for (int ks = 0; ks < 4; ++ks) {
    int qb = ks * 32 + ((lane >> 4) << 3);
    float wv[8];
#pragma unroll
    for (int e = 0; e < 8; ++e)
      wv[e] = exp2f(cl - cs[qb + e]) * dtb[(row0 + qb + e) * NHEADS + h];
    bf16x8 a[2], b[4];
#pragma unroll
    for (int fn = 0; fn < 2; ++fn) {
      int n = 32 * wave + fn * 16 + (lane & 15);
      bfpack t;
#pragma unroll
      for (int e = 0; e < 8; ++e) {
        int q = qb + e;
        float bv = bf2f(*(const u16*)((const char*)Bb + q * 256 + SWB(q, 2 * n)));
        t.u[e] = f2bf(bv * wv[e]);
      }
      a[fn] = t.v;
    }
    int kb = ks * 64 + ((lane >> 4) << 4);
#pragma unroll
    for (int fp = 0; fp < 4; ++fp) {
      int pr = fp * 16 + (lane & 15);
      b[fp] = *(const bf16x8*)((const char*)xhT + pr * 256 + SWB(pr, kb));
    }
#pragma unroll
    for (int fn = 0; fn < 2; ++fn)
#pragma unroll
      for (int fp = 0; fp < 4; ++fp)
        sa[fn][fp] = __builtin_amdgcn_mfma_f32_16x16x32_bf16(a[fn], b[fp], sa[fn][fp], 0, 0, 0);
  }
  // stage S^T[p][n] into Cc region, then coalesced copy out
  __syncthreads();
#pragma unroll
  for (int fn = 0; fn < 2; ++fn) {
    int nb = 32 * wave + fn * 16 + ((lane >> 4) << 2);
#pragma unroll
    for (int fp = 0; fp < 4; ++fp) {
      int p = fp * 16 + (lane & 15);
#pragma unroll
      for (int r = 0; r < 4; ++r)
        *(u16*)((char*)Cc + p * 256 + SWB(p, 2 * (nb + r))) = f2bf(sa[fn][fp][r]);
    }
  }
  __syncthreads();
#pragma unroll
  for (int s = 0; s < 4; ++s) {
    int idx = s * 256 + tid;
    int p = idx >> 4, n16 = idx & 15;
    uint4 v = *(const uint4*)((char*)Cc + p * 256 + SWB(p, n16 * 16));
    *(uint4*)(S + (size_t)bch * 8192 + p * 128 + n16 * 8) = v;
  }
}

// ---------------- inter-chunk scan (in place; S layout [p][n] flat 8192/bch) -------
__global__ __launch_bounds__(256) void ssd_scan(u16* __restrict__ S,
                                                const float* __restrict__ dacs) {
  int f = blockIdx.x * 256 + threadIdx.x;   // 524288 total
  int e = f & 8191;
  int bh = f >> 13;
  int b = bh >> 5, h = bh & 31;
  float carry = 0.f;
  for (int c = 0; c < NCHUNK; ++c) {
    size_t bch = ((size_t)b * 32 + c) * 32 + h;
    size_t off = bch * 8192 + e;
    float s = bf2f(S[off]);
    S[off] = f2bf(carry);
    float cd = exp2f(dacs[bch * 128 + 127]);
    carry = fmaf(carry, cd, s);
  }
}

// ---------------- Y_off: y += exp2(cs_i) * C(128x128) . prev^T-layout (MFMA) ----------------
__global__ __launch_bounds__(256) void ssd_off2(const u16* __restrict__ convb,
                                                const u16* __restrict__ S,
                                                const float* __restrict__ dacs,
                                                u16* __restrict__ y) {
  __shared__ u16 Cc[128 * 128];
  __shared__ u16 pv[64 * 128];   // prev as [p][n]
  int bch = (blockIdx.x & 7) * 256 + (blockIdx.x >> 3);
  int h = bch & 31, bc = bch >> 5;
  size_t row0 = (size_t)bc * 128;
  int tid = threadIdx.x, lane = tid & 63, wave = tid >> 6;
  const float* cs = dacs + (size_t)bch * 128;

#pragma unroll
  for (int s = 0; s < 8; ++s) {
    int idx = s * 256 + tid;
    int r = idx >> 4, n16 = idx & 15;
    uint4 v = *(const uint4*)(convb + (row0 + r) * CONVDIM + (DINNER + DSTATE) + n16 * 8);
    *(uint4*)((char*)Cc + r * 256 + SWB(r, n16 * 16)) = v;
  }
#pragma unroll
  for (int s = 0; s < 4; ++s) {
    int idx = s * 256 + tid;
    int p = idx >> 4, n16 = idx & 15;
    uint4 v = *(const uint4*)(S + (size_t)bch * 8192 + p * 128 + n16 * 8);
    *(uint4*)((char*)pv + p * 256 + SWB(p, n16 * 16)) = v;
  }
  __syncthreads();

  f32x4 acc[2][4] = {};
#pragma unroll
  for (int ks = 0; ks < 4; ++ks) {
    int kb = ks * 64 + ((lane >> 4) << 4);
    bf16x8 a[2], b[4];
#pragma unroll
    for (int fi = 0; fi < 2; ++fi) {
      int r = 32 * wave + fi * 16 + (lane & 15);
      a[fi] = *(const bf16x8*)((const char*)Cc + r * 256 + SWB(r, kb));
    }
#pragma unroll
    for (int fp = 0; fp < 4; ++fp) {
      int pr = fp * 16 + (lane & 15);
      b[fp] = *(const bf16x8*)((const char*)pv + pr * 256 + SWB(pr, kb));
    }
#pragma unroll
    for (int fi = 0; fi < 2; ++fi)
#pragma unroll
      for (int fp = 0; fp < 4; ++fp)
        acc[fi][fp] = __builtin_amdgcn_mfma_f32_16x16x32_bf16(a[fi], b[fp], acc[fi][fp], 0, 0, 0);
  }
#pragma unroll
  for (int fi = 0; fi < 2; ++fi) {
    int ib = 32 * wave + fi * 16 + ((lane >> 4) << 2);
    float ei[4];
#pragma unroll
    for (int r = 0; r < 4; ++r) ei[r] = exp2f(cs[ib + r]);
#pragma unroll
    for (int fp = 0; fp < 4; ++fp) {
      int p = fp * 16 + (lane & 15);
#pragma unroll
      for (int r = 0; r < 4; ++r) {
        u16* yp = &y[(row0 + ib + r) * DINNER + h * 64 + p];
        float cur = bf2f(*yp);
        *yp = f2bf(fmaf(ei[r], acc[fi][fp][r], cur));
      }
    }
  }
}

// ---------------- gated RMSNorm -> bf16 ----------------
__global__ __launch_bounds__(256) void gated_norm(const u16* __restrict__ y,
                                                  const u16* __restrict__ zb,
                                                  const float* __restrict__ normw,
                                                  u16* __restrict__ yb) {
  size_t bt = blockIdx.x;
  int tid = threadIdx.x;
  const u16* yr = y + bt * DINNER;
  const u16* zr = zb + bt * DINNER;
  float g[8];
  float ss = 0.f;
#pragma unroll
  for (int s = 0; s < 8; ++s) {
    int c = tid + s * 256;
    float z = bf2f(zr[c]);
    float v = bf2f(yr[c]) * (z / (1.f + __expf(-z)));
    g[s] = v;
    ss = fmaf(v, v, ss);
  }
#pragma unroll
  for (int o = 1; o < 64; o <<= 1) ss += __shfl_xor(ss, o, 64);
  __shared__ float red[4];
  if ((tid & 63) == 0) red[tid >> 6] = ss;
  __syncthreads();
  float tot = red[0] + red[1] + red[2] + red[3];
  float r = rsqrtf(tot * (1.f / (float)DINNER) + 1e-5f);
#pragma unroll
  for (int s = 0; s < 8; ++s) {
    int c = tid + s * 256;
    yb[bt * DINNER + c] = f2bf(g[s] * r * normw[c]);
  }
}

// ---------------- workspace layout (~198 MiB) ----------------
constexpr size_t SZ_XB   = (size_t)BT_TOT * DMODEL * 2;
constexpr size_t SZ_WIB  = (size_t)DINPROJ * DMODEL * 2;
constexpr size_t SZ_WOB  = (size_t)DMODEL * DINNER * 2;
constexpr size_t SZ_ZB   = (size_t)BT_TOT * DINNER * 2;
constexpr size_t SZ_XBCB = (size_t)BT_TOT * CONVDIM * 2;   // reused by yb
constexpr size_t SZ_DTB  = (size_t)BT_TOT * NHEADS * 4;
constexpr size_t SZ_DACS = (size_t)2048 * 128 * 4;
constexpr size_t SZ_CONV = (size_t)BT_TOT * CONVDIM * 2;
constexpr size_t SZ_SB   = (size_t)2048 * 128 * 64 * 2;
constexpr size_t SZ_Y    = (size_t)BT_TOT * DINNER * 2;    // bf16 now

constexpr size_t OFF_XB   = 0;
constexpr size_t OFF_WIB  = OFF_XB + SZ_XB;
constexpr size_t OFF_WOB  = OFF_WIB + SZ_WIB;
constexpr size_t OFF_ZB   = OFF_WOB + SZ_WOB;
constexpr size_t OFF_XBCB = OFF_ZB + SZ_ZB;
constexpr size_t OFF_DTB  = OFF_XBCB + SZ_XBCB;
constexpr size_t OFF_DACS = OFF_DTB + SZ_DTB;
constexpr size_t OFF_CONV = OFF_DACS + SZ_DACS;
constexpr size_t OFF_SB   = OFF_CONV + SZ_CONV;
constexpr size_t OFF_Y    = OFF_SB + SZ_SB;
constexpr size_t WS_NEEDED = OFF_Y + SZ_Y;

extern "C" void kernel_launch(void* const* d_in, const int* in_sizes, int n_in,
                              void* d_out, int out_size, void* d_ws, size_t ws_size,
                              hipStream_t stream) {
  (void)in_sizes; (void)n_in; (void)out_size;
  if (ws_size < WS_NEEDED) return;

  const float* x      = (const float*)d_in[0];
  const float* Win    = (const float*)d_in[1];
  const float* cw     = (const float*)d_in[2];
  const float* cb     = (const float*)d_in[3];
  const float* dtbias = (const float*)d_in[4];
  const float* A_log  = (const float*)d_in[5];
  const float* Dv     = (const float*)d_in[6];
  const float* normw  = (const float*)d_in[7];
  const float* Wout   = (const float*)d_in[8];
  float* out = (float*)d_out;

  char* ws = (char*)d_ws;
  u16*   xb    = (u16*)  (ws + OFF_XB);
  u16*   wib   = (u16*)  (ws + OFF_WIB);
  u16*   wob   = (u16*)  (ws + OFF_WOB);
  u16*   zb    = (u16*)  (ws + OFF_ZB);
  u16*   xbcb  = (u16*)  (ws + OFF_XBCB);
  float* dtb   = (float*)(ws + OFF_DTB);
  float* dacs  = (float*)(ws + OFF_DACS);
  u16*   convb = (u16*)  (ws + OFF_CONV);
  u16*   sb    = (u16*)  (ws + OFF_SB);
  u16*   y     = (u16*)  (ws + OFF_Y);
  u16*   yb    = (u16*)  (ws + OFF_XBCB);  // overlay: xbcb dead after conv_silu

  cast_bf16<<<dim3(4096), dim3(256), 0, stream>>>(x, xb, BT_TOT * DMODEL / 8);
  tcast<<<dim3(DINPROJ / 32, DMODEL / 32), dim3(256), 0, stream>>>(Win, wib, DMODEL, DINPROJ);
  tcast<<<dim3(DMODEL / 32, DINNER / 32), dim3(256), 0, stream>>>(Wout, wob, DINNER, DMODEL);

  gemm_in<<<dim3(35, 64), dim3(256), 0, stream>>>(xb, wib, dtbias, zb, xbcb, dtb);

  conv_silu<<<dim3(BT_TOT * (CONVDIM / 8) / 256), dim3(256), 0, stream>>>(xbcb, cw, cb, convb);
  ssd_cumsum<<<dim3(2048), dim3(128), 0, stream>>>(dtb, A_log, dacs);
  ssd_intra2<<<dim3(2048), dim3(256), 0, stream>>>(convb, dacs, dtb, Dv, y, sb);
  ssd_scan<<<dim3(2048), dim3(256), 0, stream>>>(sb, dacs);
  ssd_off2<<<dim3(2048), dim3(256), 0, stream>>>(convb, sb, dacs, y);
  gated_norm<<<dim3(BT_TOT), dim3(256), 0, stream>>>(y, zb, normw, yb);

  gemm_out<<<dim3(8, 64), dim3(256), 0, stream>>>(yb, wob, out);
}

// Round 11
// 302.925 us; speedup vs baseline: 1.4652x; 1.3545x over previous
//
#include <hip/hip_runtime.h>

typedef unsigned short u16;
typedef unsigned int   u32;

#define LOG2E 1.44269504088896340736f

// ---------------- dims ----------------
#define BT_TOT   8192      // B*T
#define SEQ      4096
#define DMODEL   1024
#define DINNER   2048
#define NHEADS   32
#define HEADDIM  64
#define DSTATE   128
#define CONVDIM  2304
#define DINPROJ  4384
#define NCHUNK   32        // per batch
#define CHUNKQ   128

typedef float  f32x4  __attribute__((ext_vector_type(4)));
typedef __bf16 bf16x8 __attribute__((ext_vector_type(8)));

// XOR swizzle of a byte offset within a 256B (or 128B) row
#define SWB(r, b) ((b) ^ (((r) & 7) << 4))

__device__ __forceinline__ u16 f2bf(float f) {
  u32 u = __float_as_uint(f);
  u += 0x7fffu + ((u >> 16) & 1u);
  return (u16)(u >> 16);
}
__device__ __forceinline__ float bf2f(u16 s) {
  return __uint_as_float(((u32)s) << 16);
}

// async global->LDS, 16B per lane; lds dest must be wave-uniform base (+lane*16 implicit)
__device__ __forceinline__ void async_cp16(const void* g, void* l) {
  __builtin_amdgcn_global_load_lds((const __attribute__((address_space(1))) u32*)g,
                                   (__attribute__((address_space(3))) u32*)l, 16, 0, 0);
}

union bfpack { u16 u[8]; bf16x8 v; };

// ---------------- cast f32 -> bf16 (8 elems/thread) ----------------
__global__ __launch_bounds__(256) void cast_bf16(const float* __restrict__ in,
                                                 u16* __restrict__ out, int n8) {
  int i = blockIdx.x * 256 + threadIdx.x;
  if (i >= n8) return;
  const float4* p = (const float4*)in + (size_t)i * 2;
  float4 a = p[0], b = p[1];
  uint4 o;
  o.x = (u32)f2bf(a.x) | ((u32)f2bf(a.y) << 16);
  o.y = (u32)f2bf(a.z) | ((u32)f2bf(a.w) << 16);
  o.z = (u32)f2bf(b.x) | ((u32)f2bf(b.y) << 16);
  o.w = (u32)f2bf(b.z) | ((u32)f2bf(b.w) << 16);
  ((uint4*)out)[i] = o;
}

// ---------------- transpose + cast: in (R,C) f32 -> out (C,R) bf16 ----------------
__global__ __launch_bounds__(256) void tcast(const float* __restrict__ in,
                                             u16* __restrict__ out, int R, int C) {
  __shared__ float tile[32][33];
  int c0 = blockIdx.x * 32, r0 = blockIdx.y * 32;
  int tx = threadIdx.x & 31, ty = threadIdx.x >> 5;  // ty 0..7
  for (int dy = 0; dy < 32; dy += 8)
    tile[ty + dy][tx] = in[(size_t)(r0 + ty + dy) * C + c0 + tx];
  __syncthreads();
  for (int dy = 0; dy < 32; dy += 8)
    out[(size_t)(c0 + ty + dy) * R + r0 + tx] = f2bf(tile[tx][ty + dy]);
}

// ================= GEMM cores (round-4 proven: 128x128, BK=64, 2-phase, 64KB LDS,
//                  2 blocks/CU -> inter-block overlap hides the barrier drain) =====

// ---- GEMM1: zxbcdt = xb @ Win^T with split epilogue ----
__global__ __launch_bounds__(256) void gemm_in(const u16* __restrict__ A,
                                               const u16* __restrict__ Bt,
                                               const float* __restrict__ dt_bias,
                                               u16* __restrict__ zb,
                                               u16* __restrict__ xbcb,
                                               float* __restrict__ dtb) {
  const int K = DMODEL, Nn = DINPROJ;
  __shared__ u16 sh[32768];
  const int tid = threadIdx.x, lane = tid & 63, wave = tid >> 6;
  const int wm = (wave >> 1) << 6, wn = (wave & 1) << 6;
  // XCD swizzle (nwg = 35*64 = 2240, %8==0)
  int flat = blockIdx.y * gridDim.x + blockIdx.x;
  int cpx = (gridDim.x * gridDim.y) >> 3;
  int swz = (flat & 7) * cpx + (flat >> 3);
  const int m0 = (swz / gridDim.x) * 128;
  const int n0 = (swz % gridDim.x) * 128;

  f32x4 acc[4][4] = {};

  auto issue = [&](int buf, int k0) {
#pragma unroll
    for (int s = 0; s < 4; ++s) {
      int idx = s * 256 + tid;
      int row = idx >> 3, k16 = idx & 7;
      int swo = (k16 * 8) ^ ((row & 7) << 3);          // u16 units
      int lofs = (s * 256 + wave * 64) * 8;            // wave-uniform u16 offset
      async_cp16(A + (size_t)(m0 + row) * K + k0 + swo, sh + buf * 16384 + lofs);
      int rn = n0 + row; if (rn > Nn - 1) rn = Nn - 1;
      async_cp16(Bt + (size_t)rn * K + k0 + swo, sh + buf * 16384 + 8192 + lofs);
    }
  };
  issue(0, 0);
  const int nk = K / 64;
  for (int kt = 0; kt < nk; ++kt) {
    int buf = kt & 1;
    asm volatile("s_waitcnt vmcnt(0)" ::: "memory");
    __syncthreads();
    if (kt + 1 < nk) issue(buf ^ 1, (kt + 1) * 64);
    const char* As = (const char*)(sh + buf * 16384);
    const char* Bs = (const char*)(sh + buf * 16384 + 8192);
#pragma unroll
    for (int ks = 0; ks < 2; ++ks) {
      bf16x8 af[4], bfr[4];
#pragma unroll
      for (int t = 0; t < 4; ++t) {
        int r  = wm + t * 16 + (lane & 15);
        int kb = ks * 64 + ((lane >> 4) << 4);
        af[t]  = *(const bf16x8*)(As + r * 128 + SWB(r, kb));
        int rn = wn + t * 16 + (lane & 15);
        bfr[t] = *(const bf16x8*)(Bs + rn * 128 + SWB(rn, kb));
      }
#pragma unroll
      for (int mi = 0; mi < 4; ++mi)
#pragma unroll
        for (int ni = 0; ni < 4; ++ni)
          acc[mi][ni] = __builtin_amdgcn_mfma_f32_16x16x32_bf16(af[mi], bfr[ni], acc[mi][ni], 0, 0, 0);
    }
  }
  __syncthreads();
  if (n0 == 4352) {  // dt block: scalar softplus epilogue (only 32 valid cols)
#pragma unroll
    for (int mi = 0; mi < 4; ++mi) {
#pragma unroll
      for (int ni = 0; ni < 4; ++ni) {
        int r0 = m0 + wm + mi * 16 + ((lane >> 4) << 2);
        int c  = n0 + wn + ni * 16 + (lane & 15);
        if (c < DINPROJ) {
          int h = c - 4352;
          float bias = dt_bias[h];
#pragma unroll
          for (int j = 0; j < 4; ++j) {
            float v = acc[mi][ni][j] + bias;
            dtb[(size_t)(r0 + j) * NHEADS + h] = (v > 20.f) ? v : log1pf(__expf(v));
          }
        }
      }
    }
  } else {
    // stage bf16 tile into LDS, then coalesced uint4 writes
#pragma unroll
    for (int mi = 0; mi < 4; ++mi)
#pragma unroll
      for (int ni = 0; ni < 4; ++ni) {
        int il = wm + mi * 16 + ((lane >> 4) << 2);
        int cl = wn + ni * 16 + (lane & 15);
#pragma unroll
        for (int j = 0; j < 4; ++j)
          *(u16*)((char*)sh + (il + j) * 256 + SWB(il + j, 2 * cl)) = f2bf(acc[mi][ni][j]);
      }
    __syncthreads();
    u16* dst; int ldst, n0c;
    if (n0 < 2048) { dst = zb;   ldst = DINNER;  n0c = n0; }
    else           { dst = xbcb; ldst = CONVDIM; n0c = n0 - 2048; }
#pragma unroll
    for (int s = 0; s < 8; ++s) {   // 128 rows x 16 uint4 = 2048 = 8*256
      int idx = s * 256 + tid;
      int r = idx >> 4, n16 = idx & 15;
      uint4 v = *(const uint4*)((char*)sh + r * 256 + SWB(r, n16 * 16));
      *(uint4*)(dst + (size_t)(m0 + r) * ldst + n0c + n16 * 8) = v;
    }
  }
}

// ---- GEMM2: out = yb @ Wout^T, f32 output ----
__global__ __launch_bounds__(256) void gemm_out(const u16* __restrict__ A,
                                                const u16* __restrict__ Bt,
                                                float* __restrict__ C) {
  const int K = DINNER, Nn = DMODEL;
  __shared__ u16 sh[32768];
  const int tid = threadIdx.x, lane = tid & 63, wave = tid >> 6;
  const int wm = (wave >> 1) << 6, wn = (wave & 1) << 6;
  int flat = blockIdx.y * gridDim.x + blockIdx.x;   // nwg = 8*64 = 512
  int cpx = (gridDim.x * gridDim.y) >> 3;
  int swz = (flat & 7) * cpx + (flat >> 3);
  const int m0 = (swz / gridDim.x) * 128;
  const int n0 = (swz % gridDim.x) * 128;

  f32x4 acc[4][4] = {};
  auto issue = [&](int buf, int k0) {
#pragma unroll
    for (int s = 0; s < 4; ++s) {
      int idx = s * 256 + tid;
      int row = idx >> 3, k16 = idx & 7;
      int swo = (k16 * 8) ^ ((row & 7) << 3);
      int lofs = (s * 256 + wave * 64) * 8;
      async_cp16(A + (size_t)(m0 + row) * K + k0 + swo, sh + buf * 16384 + lofs);
      async_cp16(Bt + (size_t)(n0 + row) * K + k0 + swo, sh + buf * 16384 + 8192 + lofs);
    }
  };
  issue(0, 0);
  const int nk = K / 64;
  for (int kt = 0; kt < nk; ++kt) {
    int buf = kt & 1;
    asm volatile("s_waitcnt vmcnt(0)" ::: "memory");
    __syncthreads();
    if (kt + 1 < nk) issue(buf ^ 1, (kt + 1) * 64);
    const char* As = (const char*)(sh + buf * 16384);
    const char* Bs = (const char*)(sh + buf * 16384 + 8192);
#pragma unroll
    for (int ks = 0; ks < 2; ++ks) {
      bf16x8 af[4], bfr[4];
#pragma unroll
      for (int t = 0; t < 4; ++t) {
        int r  = wm + t * 16 + (lane & 15);
        int kb = ks * 64 + ((lane >> 4) << 4);
        af[t]  = *(const bf16x8*)(As + r * 128 + SWB(r, kb));
        int rn = wn + t * 16 + (lane & 15);
        bfr[t] = *(const bf16x8*)(Bs + rn * 128 + SWB(rn, kb));
      }
#pragma unroll
      for (int mi = 0; mi < 4; ++mi)
#pragma unroll
        for (int ni = 0; ni < 4; ++ni)
          acc[mi][ni] = __builtin_amdgcn_mfma_f32_16x16x32_bf16(af[mi], bfr[ni], acc[mi][ni], 0, 0, 0);
    }
  }
#pragma unroll
  for (int mi = 0; mi < 4; ++mi) {
#pragma unroll
    for (int ni = 0; ni < 4; ++ni) {
      int r0 = m0 + wm + mi * 16 + ((lane >> 4) << 2);
      int c  = n0 + wn + ni * 16 + (lane & 15);
#pragma unroll
      for (int j = 0; j < 4; ++j)
        C[(size_t)(r0 + j) * Nn + c] = acc[mi][ni][j];
    }
  }
}

// -------- depthwise causal conv1d + bias + silu: 8 ch x 4 timesteps per thread --------
// cw loads are CONTIGUOUS 128B per thread (8 x float4), amortized over 4 outputs;
// tap rows held in registers (7 x uint4), read amplification 1.75x instead of 4x.
__global__ __launch_bounds__(256) void conv_silu(const u16* __restrict__ xbcb,
                                                 const float* __restrict__ cw,
                                                 const float* __restrict__ cb,
                                                 u16* __restrict__ convb) {
  int i = blockIdx.x * 256 + threadIdx.x;   // (BT_TOT/4) * 288 threads
  int bt4 = i / 288, c8 = i - bt4 * 288;
  int c0 = c8 * 8;
  int bt = bt4 * 4;                          // base output row (4 outputs: bt..bt+3)
  int t = bt & (SEQ - 1);

  // weights: channel c0+q, taps 0..3 in w[q]; contiguous 128B
  float4 w[8];
  const float4* wp = (const float4*)(cw + (size_t)c0 * 4);
#pragma unroll
  for (int q = 0; q < 8; ++q) w[q] = wp[q];
  float4 b0 = ((const float4*)(cb + c0))[0];
  float4 b1 = ((const float4*)(cb + c0))[1];
  float bias[8] = {b0.x, b0.y, b0.z, b0.w, b1.x, b1.y, b1.z, b1.w};

  // 7 tap rows: bt-3 .. bt+3 (rix 0..6); invalid only when t==0 (batch start)
  uint4 rows[7];
#pragma unroll
  for (int rix = 0; rix < 7; ++rix) {
    if (t - 3 + rix >= 0)
      rows[rix] = *(const uint4*)(xbcb + (size_t)(bt - 3 + rix) * CONVDIM + c0);
    else
      rows[rix] = make_uint4(0, 0, 0, 0);   // bf16 zero bits
  }

#pragma unroll
  for (int j = 0; j < 4; ++j) {
    float acc[8];
#pragma unroll
    for (int e = 0; e < 8; ++e) acc[e] = bias[e];
#pragma unroll
    for (int k = 0; k < 4; ++k) {
      const u16* e16 = (const u16*)&rows[j + k];
      float wk;
#pragma unroll
      for (int e = 0; e < 8; ++e) {
        wk = (k == 0) ? w[e].x : (k == 1) ? w[e].y : (k == 2) ? w[e].z : w[e].w;
        acc[e] = fmaf(bf2f(e16[e]), wk, acc[e]);
      }
    }
    uint4 o;
    u16* o16 = (u16*)&o;
#pragma unroll
    for (int e = 0; e < 8; ++e) {
      float s = acc[e] / (1.f + __expf(-acc[e]));
      o16[e] = f2bf(s);
    }
    *(uint4*)(convb + (size_t)(bt + j) * CONVDIM + c0) = o;
  }
}

// ---------------- per-(b,c,h) cumsum of dA over chunk; stores LOG2-domain ----------------
__global__ __launch_bounds__(128) void ssd_cumsum(const float* __restrict__ dtb,
                                                  const float* __restrict__ A_log,
                                                  float* __restrict__ dacs) {
  int bch = blockIdx.x;          // (b*32+c)*32+h
  int h = bch & 31, bc = bch >> 5;
  int q = threadIdx.x;
  float A = -__expf(A_log[h]);
  float v = dtb[((size_t)bc * 128 + q) * 32 + h] * A;
#pragma unroll
  for (int o = 1; o < 64; o <<= 1) {
    float u = __shfl_up(v, o, 64);
    if ((q & 63) >= o) v += u;
  }
  __shared__ float w0;
  if (q == 63) w0 = v;
  __syncthreads();
  if (q >= 64) v += w0;
  dacs[(size_t)bch * 128 + q] = v * LOG2E;
}

// ---------------- fused SSD intra per (b,c,h): G -> M -> Y_diag (+D*xh), S^T ----------------
__global__ __launch_bounds__(256) void ssd_intra2(const u16* __restrict__ convb,
                                                  const float* __restrict__ dacs,
                                                  const float* __restrict__ dtb,
                                                  const float* __restrict__ Dv,
                                                  u16* __restrict__ y,
                                                  u16* __restrict__ S) {
  __shared__ u16 Cc[128 * 128];
  __shared__ u16 Bb[128 * 128];
  __shared__ u16 xhT[64 * 128];
  int bch = (blockIdx.x & 7) * 256 + (blockIdx.x >> 3);  // XCD swizzle (2048 %8==0)
  int h = bch & 31, bc = bch >> 5;
  size_t row0 = (size_t)bc * 128;
  int tid = threadIdx.x, lane = tid & 63, wave = tid >> 6;
  const float* cs = dacs + (size_t)bch * 128;   // log2-domain cumsum

  // ---- stage C,B (swizzled rows) and xh transposed ----
#pragma unroll
  for (int s = 0; s < 8; ++s) {
    int idx = s * 256 + tid;
    int r = idx >> 4, n16 = idx & 15;
    uint4 v = *(const uint4*)(convb + (row0 + r) * CONVDIM + (DINNER + DSTATE) + n16 * 8);
    *(uint4*)((char*)Cc + r * 256 + SWB(r, n16 * 16)) = v;
    uint4 w = *(const uint4*)(convb + (row0 + r) * CONVDIM + DINNER + n16 * 8);
    *(uint4*)((char*)Bb + r * 256 + SWB(r, n16 * 16)) = w;
  }
#pragma unroll
  for (int s = 0; s < 4; ++s) {
    int idx = s * 256 + tid;
    int q = idx >> 3, p0 = (idx & 7) * 8;
    uint4 v = *(const uint4*)(convb + (row0 + q) * CONVDIM + h * 64 + p0);
    const u16* e = (const u16*)&v;
#pragma unroll
    for (int k = 0; k < 8; ++k)
      *(u16*)((char*)xhT + (p0 + k) * 256 + SWB(p0 + k, 2 * q)) = e[k];
  }
  __syncthreads();

  // ---- G = C . B^T (k = n over 128): wave owns i rows [32w, 32w+32) ----
  f32x4 g[2][8] = {};
#pragma unroll
  for (int ks = 0; ks < 4; ++ks) {
    int kb = ks * 64 + ((lane >> 4) << 4);
    bf16x8 a[2], b[8];
#pragma unroll
    for (int fi = 0; fi < 2; ++fi) {
      int r = 32 * wave + fi * 16 + (lane & 15);
      a[fi] = *(const bf16x8*)((const char*)Cc + r * 256 + SWB(r, kb));
    }
#pragma unroll
    for (int fj = 0; fj < 8; ++fj) {
      int rj = fj * 16 + (lane & 15);
      b[fj] = *(const bf16x8*)((const char*)Bb + rj * 256 + SWB(rj, kb));
    }
#pragma unroll
    for (int fi = 0; fi < 2; ++fi)
#pragma unroll
      for (int fj = 0; fj < 8; ++fj)
        g[fi][fj] = __builtin_amdgcn_mfma_f32_16x16x32_bf16(a[fi], b[fj], g[fi][fj], 0, 0, 0);
  }

  // ---- build M (bf16) into Cc rows owned by this wave ----
#pragma unroll
  for (int fi = 0; fi < 2; ++fi) {
    int ib = 32 * wave + fi * 16 + ((lane >> 4) << 2);
    float ci[4];
#pragma unroll
    for (int r = 0; r < 4; ++r) ci[r] = cs[ib + r];
#pragma unroll
    for (int fj = 0; fj < 8; ++fj) {
      int j = fj * 16 + (lane & 15);
      float cj = cs[j];
      float dj = dtb[(row0 + j) * NHEADS + h];
#pragma unroll
      for (int r = 0; r < 4; ++r) {
        int i = ib + r;
        float m = (j <= i) ? g[fi][fj][r] * exp2f(ci[r] - cj) * dj : 0.f;
        *(u16*)((char*)Cc + i * 256 + SWB(i, 2 * j)) = f2bf(m);
      }
    }
  }

  // ---- Y_diag = M . xh (k = j), triangular k-skip; + D*xh; store y (bf16) ----
  f32x4 yd[2][4] = {};
  for (int ks = 0; ks <= wave; ++ks) {
    int kb = ks * 64 + ((lane >> 4) << 4);
    bf16x8 a[2], b[4];
#pragma unroll
    for (int fi = 0; fi < 2; ++fi) {
      int r = 32 * wave + fi * 16 + (lane & 15);
      a[fi] = *(const bf16x8*)((const char*)Cc + r * 256 + SWB(r, kb));
    }
#pragma unroll
    for (int fp = 0; fp < 4; ++fp) {
      int pr = fp * 16 + (lane & 15);
      b[fp] = *(const bf16x8*)((const char*)xhT + pr * 256 + SWB(pr, kb));
    }
#pragma unroll
    for (int fi = 0; fi < 2; ++fi)
#pragma unroll
      for (int fp = 0; fp < 4; ++fp)
        yd[fi][fp] = __builtin_amdgcn_mfma_f32_16x16x32_bf16(a[fi], b[fp], yd[fi][fp], 0, 0, 0);
  }
  {
    float Dh = Dv[h];
#pragma unroll
    for (int fi = 0; fi < 2; ++fi) {
      int ib = 32 * wave + fi * 16 + ((lane >> 4) << 2);
#pragma unroll
      for (int fp = 0; fp < 4; ++fp) {
        int p = fp * 16 + (lane & 15);
#pragma unroll
        for (int r = 0; r < 4; ++r) {
          int i = ib + r;
          float xv = bf2f(*(const u16*)((const char*)xhT + p * 256 + SWB(p, 2 * i)));
          y[(row0 + i) * DINNER + h * 64 + p] = f2bf(yd[fi][fp][r] + Dh * xv);
        }
      }
    }
  }

  // ---- S[n][p] = sum_q (B[q][n]*w_q) * xh[q][p] (k = q); wave owns n rows ----
  float cl = cs[127];
  f32x4 sa[2][4] = {};
#pragma unroll
  for (int ks = 0; ks < 4; ++ks) {
    int qb = ks * 32 + ((lane >> 4) << 3);
    float wv[8];
#pragma unroll
    for (int e = 0; e < 8; ++e)
      wv[e] = exp2f(cl - cs[qb + e]) * dtb[(row0 + qb + e) * NHEADS + h];
    bf16x8 a[2], b[4];
#pragma unroll
    for (int fn = 0; fn < 2; ++fn) {
      int n = 32 * wave + fn * 16 + (lane & 15);
      bfpack t;
#pragma unroll
      for (int e = 0; e < 8; ++e) {
        int q = qb + e;
        float bv = bf2f(*(const u16*)((const char*)Bb + q * 256 + SWB(q, 2 * n)));
        t.u[e] = f2bf(bv * wv[e]);
      }
      a[fn] = t.v;
    }
    int kb = ks * 64 + ((lane >> 4) << 4);
#pragma unroll
    for (int fp = 0; fp < 4; ++fp) {
      int pr = fp * 16 + (lane & 15);
      b[fp] = *(const bf16x8*)((const char*)xhT + pr * 256 + SWB(pr, kb));
    }
#pragma unroll
    for (int fn = 0; fn < 2; ++fn)
#pragma unroll
      for (int fp = 0; fp < 4; ++fp)
        sa[fn][fp] = __builtin_amdgcn_mfma_f32_16x16x32_bf16(a[fn], b[fp], sa[fn][fp], 0, 0, 0);
  }
  // stage S^T[p][n] into Cc region, then coalesced copy out
  __syncthreads();
#pragma unroll
  for (int fn = 0; fn < 2; ++fn) {
    int nb = 32 * wave + fn * 16 + ((lane >> 4) << 2);
#pragma unroll
    for (int fp = 0; fp < 4; ++fp) {
      int p = fp * 16 + (lane & 15);
#pragma unroll
      for (int r = 0; r < 4; ++r)
        *(u16*)((char*)Cc + p * 256 + SWB(p, 2 * (nb + r))) = f2bf(sa[fn][fp][r]);
    }
  }
  __syncthreads();
#pragma unroll
  for (int s = 0; s < 4; ++s) {
    int idx = s * 256 + tid;
    int p = idx >> 4, n16 = idx & 15;
    uint4 v = *(const uint4*)((char*)Cc + p * 256 + SWB(p, n16 * 16));
    *(uint4*)(S + (size_t)bch * 8192 + p * 128 + n16 * 8) = v;
  }
}

// ---------------- inter-chunk scan (in place; S layout [p][n] flat 8192/bch) -------
__global__ __launch_bounds__(256) void ssd_scan(u16* __restrict__ S,
                                                const float* __restrict__ dacs) {
  int f = blockIdx.x * 256 + threadIdx.x;   // 524288 total
  int e = f & 8191;
  int bh = f >> 13;
  int b = bh >> 5, h = bh & 31;
  float carry = 0.f;
  for (int c = 0; c < NCHUNK; ++c) {
    size_t bch = ((size_t)b * 32 + c) * 32 + h;
    size_t off = bch * 8192 + e;
    float s = bf2f(S[off]);
    S[off] = f2bf(carry);
    float cd = exp2f(dacs[bch * 128 + 127]);
    carry = fmaf(carry, cd, s);
  }
}

// ---------------- Y_off: y += exp2(cs_i) * C(128x128) . prev^T-layout (MFMA) ----------------
__global__ __launch_bounds__(256) void ssd_off2(const u16* __restrict__ convb,
                                                const u16* __restrict__ S,
                                                const float* __restrict__ dacs,
                                                u16* __restrict__ y) {
  __shared__ u16 Cc[128 * 128];
  __shared__ u16 pv[64 * 128];   // prev as [p][n]
  int bch = (blockIdx.x & 7) * 256 + (blockIdx.x >> 3);
  int h = bch & 31, bc = bch >> 5;
  size_t row0 = (size_t)bc * 128;
  int tid = threadIdx.x, lane = tid & 63, wave = tid >> 6;
  const float* cs = dacs + (size_t)bch * 128;

#pragma unroll
  for (int s = 0; s < 8; ++s) {
    int idx = s * 256 + tid;
    int r = idx >> 4, n16 = idx & 15;
    uint4 v = *(const uint4*)(convb + (row0 + r) * CONVDIM + (DINNER + DSTATE) + n16 * 8);
    *(uint4*)((char*)Cc + r * 256 + SWB(r, n16 * 16)) = v;
  }
#pragma unroll
  for (int s = 0; s < 4; ++s) {
    int idx = s * 256 + tid;
    int p = idx >> 4, n16 = idx & 15;
    uint4 v = *(const uint4*)(S + (size_t)bch * 8192 + p * 128 + n16 * 8);
    *(uint4*)((char*)pv + p * 256 + SWB(p, n16 * 16)) = v;
  }
  __syncthreads();

  f32x4 acc[2][4] = {};
#pragma unroll
  for (int ks = 0; ks < 4; ++ks) {
    int kb = ks * 64 + ((lane >> 4) << 4);
    bf16x8 a[2], b[4];
#pragma unroll
    for (int fi = 0; fi < 2; ++fi) {
      int r = 32 * wave + fi * 16 + (lane & 15);
      a[fi] = *(const bf16x8*)((const char*)Cc + r * 256 + SWB(r, kb));
    }
#pragma unroll
    for (int fp = 0; fp < 4; ++fp) {
      int pr = fp * 16 + (lane & 15);
      b[fp] = *(const bf16x8*)((const char*)pv + pr * 256 + SWB(pr, kb));
    }
#pragma unroll
    for (int fi = 0; fi < 2; ++fi)
#pragma unroll
      for (int fp = 0; fp < 4; ++fp)
        acc[fi][fp] = __builtin_amdgcn_mfma_f32_16x16x32_bf16(a[fi], b[fp], acc[fi][fp], 0, 0, 0);
  }
#pragma unroll
  for (int fi = 0; fi < 2; ++fi) {
    int ib = 32 * wave + fi * 16 + ((lane >> 4) << 2);
    float ei[4];
#pragma unroll
    for (int r = 0; r < 4; ++r) ei[r] = exp2f(cs[ib + r]);
#pragma unroll
    for (int fp = 0; fp < 4; ++fp) {
      int p = fp * 16 + (lane & 15);
#pragma unroll
      for (int r = 0; r < 4; ++r) {
        u16* yp = &y[(row0 + ib + r) * DINNER + h * 64 + p];
        float cur = bf2f(*yp);
        *yp = f2bf(fmaf(ei[r], acc[fi][fp][r], cur));
      }
    }
  }
}

// ---------------- gated RMSNorm -> bf16 ----------------
__global__ __launch_bounds__(256) void gated_norm(const u16* __restrict__ y,
                                                  const u16* __restrict__ zb,
                                                  const float* __restrict__ normw,
                                                  u16* __restrict__ yb) {
  size_t bt = blockIdx.x;
  int tid = threadIdx.x;
  const u16* yr = y + bt * DINNER;
  const u16* zr = zb + bt * DINNER;
  float g[8];
  float ss = 0.f;
#pragma unroll
  for (int s = 0; s < 8; ++s) {
    int c = tid + s * 256;
    float z = bf2f(zr[c]);
    float v = bf2f(yr[c]) * (z / (1.f + __expf(-z)));
    g[s] = v;
    ss = fmaf(v, v, ss);
  }
#pragma unroll
  for (int o = 1; o < 64; o <<= 1) ss += __shfl_xor(ss, o, 64);
  __shared__ float red[4];
  if ((tid & 63) == 0) red[tid >> 6] = ss;
  __syncthreads();
  float tot = red[0] + red[1] + red[2] + red[3];
  float r = rsqrtf(tot * (1.f / (float)DINNER) + 1e-5f);
#pragma unroll
  for (int s = 0; s < 8; ++s) {
    int c = tid + s * 256;
    yb[bt * DINNER + c] = f2bf(g[s] * r * normw[c]);
  }
}

// ---------------- workspace layout (~198 MiB) ----------------
constexpr size_t SZ_XB   = (size_t)BT_TOT * DMODEL * 2;
constexpr size_t SZ_WIB  = (size_t)DINPROJ * DMODEL * 2;
constexpr size_t SZ_WOB  = (size_t)DMODEL * DINNER * 2;
constexpr size_t SZ_ZB   = (size_t)BT_TOT * DINNER * 2;
constexpr size_t SZ_XBCB = (size_t)BT_TOT * CONVDIM * 2;   // reused by yb
constexpr size_t SZ_DTB  = (size_t)BT_TOT * NHEADS * 4;
constexpr size_t SZ_DACS = (size_t)2048 * 128 * 4;
constexpr size_t SZ_CONV = (size_t)BT_TOT * CONVDIM * 2;
constexpr size_t SZ_SB   = (size_t)2048 * 128 * 64 * 2;
constexpr size_t SZ_Y    = (size_t)BT_TOT * DINNER * 2;    // bf16

constexpr size_t OFF_XB   = 0;
constexpr size_t OFF_WIB  = OFF_XB + SZ_XB;
constexpr size_t OFF_WOB  = OFF_WIB + SZ_WIB;
constexpr size_t OFF_ZB   = OFF_WOB + SZ_WOB;
constexpr size_t OFF_XBCB = OFF_ZB + SZ_ZB;
constexpr size_t OFF_DTB  = OFF_XBCB + SZ_XBCB;
constexpr size_t OFF_DACS = OFF_DTB + SZ_DTB;
constexpr size_t OFF_CONV = OFF_DACS + SZ_DACS;
constexpr size_t OFF_SB   = OFF_CONV + SZ_CONV;
constexpr size_t OFF_Y    = OFF_SB + SZ_SB;
constexpr size_t WS_NEEDED = OFF_Y + SZ_Y;

extern "C" void kernel_launch(void* const* d_in, const int* in_sizes, int n_in,
                              void* d_out, int out_size, void* d_ws, size_t ws_size,
                              hipStream_t stream) {
  (void)in_sizes; (void)n_in; (void)out_size;
  if (ws_size < WS_NEEDED) return;

  const float* x      = (const float*)d_in[0];
  const float* Win    = (const float*)d_in[1];
  const float* cw     = (const float*)d_in[2];
  const float* cb     = (const float*)d_in[3];
  const float* dtbias = (const float*)d_in[4];
  const float* A_log  = (const float*)d_in[5];
  const float* Dv     = (const float*)d_in[6];
  const float* normw  = (const float*)d_in[7];
  const float* Wout   = (const float*)d_in[8];
  float* out = (float*)d_out;

  char* ws = (char*)d_ws;
  u16*   xb    = (u16*)  (ws + OFF_XB);
  u16*   wib   = (u16*)  (ws + OFF_WIB);
  u16*   wob   = (u16*)  (ws + OFF_WOB);
  u16*   zb    = (u16*)  (ws + OFF_ZB);
  u16*   xbcb  = (u16*)  (ws + OFF_XBCB);
  float* dtb   = (float*)(ws + OFF_DTB);
  float* dacs  = (float*)(ws + OFF_DACS);
  u16*   convb = (u16*)  (ws + OFF_CONV);
  u16*   sb    = (u16*)  (ws + OFF_SB);
  u16*   y     = (u16*)  (ws + OFF_Y);
  u16*   yb    = (u16*)  (ws + OFF_XBCB);  // overlay: xbcb dead after conv_silu

  cast_bf16<<<dim3(4096), dim3(256), 0, stream>>>(x, xb, BT_TOT * DMODEL / 8);
  tcast<<<dim3(DINPROJ / 32, DMODEL / 32), dim3(256), 0, stream>>>(Win, wib, DMODEL, DINPROJ);
  tcast<<<dim3(DMODEL / 32, DINNER / 32), dim3(256), 0, stream>>>(Wout, wob, DINNER, DMODEL);

  gemm_in<<<dim3(35, 64), dim3(256), 0, stream>>>(xb, wib, dtbias, zb, xbcb, dtb);

  conv_silu<<<dim3((BT_TOT / 4) * (CONVDIM / 8) / 256), dim3(256), 0, stream>>>(
      xbcb, cw, cb, convb);
  ssd_cumsum<<<dim3(2048), dim3(128), 0, stream>>>(dtb, A_log, dacs);
  ssd_intra2<<<dim3(2048), dim3(256), 0, stream>>>(convb, dacs, dtb, Dv, y, sb);
  ssd_scan<<<dim3(2048), dim3(256), 0, stream>>>(sb, dacs);
  ssd_off2<<<dim3(2048), dim3(256), 0, stream>>>(convb, sb, dacs, y);
  gated_norm<<<dim3(BT_TOT), dim3(256), 0, stream>>>(y, zb, normw, yb);

  gemm_out<<<dim3(8, 64), dim3(256), 0, stream>>>(yb, wob, out);
}

// Round 12
// 292.851 us; speedup vs baseline: 1.5156x; 1.0344x over previous
//
#include <hip/hip_runtime.h>

typedef unsigned short u16;
typedef unsigned int   u32;

#define LOG2E 1.44269504088896340736f

// ---------------- dims ----------------
#define BT_TOT   8192      // B*T
#define SEQ      4096
#define DMODEL   1024
#define DINNER   2048
#define NHEADS   32
#define HEADDIM  64
#define DSTATE   128
#define CONVDIM  2304
#define DINPROJ  4384
#define NCHUNK   32        // per batch
#define CHUNKQ   128

typedef float  f32x4  __attribute__((ext_vector_type(4)));
typedef __bf16 bf16x8 __attribute__((ext_vector_type(8)));

// XOR swizzle of a byte offset within a 256B (or 128B) row
#define SWB(r, b) ((b) ^ (((r) & 7) << 4))

__device__ __forceinline__ u16 f2bf(float f) {
  u32 u = __float_as_uint(f);
  u += 0x7fffu + ((u >> 16) & 1u);
  return (u16)(u >> 16);
}
__device__ __forceinline__ float bf2f(u16 s) {
  return __uint_as_float(((u32)s) << 16);
}

// async global->LDS, 16B per lane; lds dest must be wave-uniform base (+lane*16 implicit)
__device__ __forceinline__ void async_cp16(const void* g, void* l) {
  __builtin_amdgcn_global_load_lds((const __attribute__((address_space(1))) u32*)g,
                                   (__attribute__((address_space(3))) u32*)l, 16, 0, 0);
}

union bfpack { u16 u[8]; bf16x8 v; };

// ---------------- cast f32 -> bf16 (8 elems/thread) ----------------
__global__ __launch_bounds__(256) void cast_bf16(const float* __restrict__ in,
                                                 u16* __restrict__ out, int n8) {
  int i = blockIdx.x * 256 + threadIdx.x;
  if (i >= n8) return;
  const float4* p = (const float4*)in + (size_t)i * 2;
  float4 a = p[0], b = p[1];
  uint4 o;
  o.x = (u32)f2bf(a.x) | ((u32)f2bf(a.y) << 16);
  o.y = (u32)f2bf(a.z) | ((u32)f2bf(a.w) << 16);
  o.z = (u32)f2bf(b.x) | ((u32)f2bf(b.y) << 16);
  o.w = (u32)f2bf(b.z) | ((u32)f2bf(b.w) << 16);
  ((uint4*)out)[i] = o;
}

// ---------------- transpose + cast: in (R,C) f32 -> out (C,R) bf16 ----------------
__global__ __launch_bounds__(256) void tcast(const float* __restrict__ in,
                                             u16* __restrict__ out, int R, int C) {
  __shared__ float tile[32][33];
  int c0 = blockIdx.x * 32, r0 = blockIdx.y * 32;
  int tx = threadIdx.x & 31, ty = threadIdx.x >> 5;  // ty 0..7
  for (int dy = 0; dy < 32; dy += 8)
    tile[ty + dy][tx] = in[(size_t)(r0 + ty + dy) * C + c0 + tx];
  __syncthreads();
  for (int dy = 0; dy < 32; dy += 8)
    out[(size_t)(c0 + ty + dy) * R + r0 + tx] = f2bf(tile[tx][ty + dy]);
}

// ================= GEMM cores (round-4 proven: 128x128, BK=64, 2-phase, 64KB LDS,
//   2 blocks/CU -> inter-block overlap hides the barrier drain).
//   Block mapping: XCD-chunked + L2-PANEL ordering (8n x 8m per panel -> ~4MB
//   working set fits the 4MB per-XCD L2; B no longer evicts itself every m-row).

// ---- GEMM1: zxbcdt = xb @ Win^T with split epilogue ----
__global__ __launch_bounds__(256) void gemm_in(const u16* __restrict__ A,
                                               const u16* __restrict__ Bt,
                                               const float* __restrict__ dt_bias,
                                               u16* __restrict__ zb,
                                               u16* __restrict__ xbcb,
                                               float* __restrict__ dtb) {
  const int K = DMODEL, Nn = DINPROJ;
  __shared__ u16 sh[32768];
  const int tid = threadIdx.x, lane = tid & 63, wave = tid >> 6;
  const int wm = (wave >> 1) << 6, wn = (wave & 1) << 6;
  // XCD chunk + panel order: grid (35,64) -> 2240 blocks, 280/XCD (8 m-rows x 35 n).
  // Panels of 8n x 8m (last panel 3n x 8m): WS = 2MB A + 2MB B fits 4MB L2.
  int flat = blockIdx.y * gridDim.x + blockIdx.x;
  int xcd = flat & 7, c = flat >> 3;          // c in [0,280)
  int dm, n;
  if (c < 256) { int p = c >> 6, r = c & 63; n = p * 8 + (r & 7); dm = r >> 3; }
  else         { int r = c - 256;            n = 32 + r % 3;      dm = r / 3;  }
  const int m0 = (xcd * 8 + dm) * 128;
  const int n0 = n * 128;

  f32x4 acc[4][4] = {};

  auto issue = [&](int buf, int k0) {
#pragma unroll
    for (int s = 0; s < 4; ++s) {
      int idx = s * 256 + tid;
      int row = idx >> 3, k16 = idx & 7;
      int swo = (k16 * 8) ^ ((row & 7) << 3);          // u16 units
      int lofs = (s * 256 + wave * 64) * 8;            // wave-uniform u16 offset
      async_cp16(A + (size_t)(m0 + row) * K + k0 + swo, sh + buf * 16384 + lofs);
      int rn = n0 + row; if (rn > Nn - 1) rn = Nn - 1;
      async_cp16(Bt + (size_t)rn * K + k0 + swo, sh + buf * 16384 + 8192 + lofs);
    }
  };
  issue(0, 0);
  const int nk = K / 64;
  for (int kt = 0; kt < nk; ++kt) {
    int buf = kt & 1;
    asm volatile("s_waitcnt vmcnt(0)" ::: "memory");
    __syncthreads();
    if (kt + 1 < nk) issue(buf ^ 1, (kt + 1) * 64);
    const char* As = (const char*)(sh + buf * 16384);
    const char* Bs = (const char*)(sh + buf * 16384 + 8192);
#pragma unroll
    for (int ks = 0; ks < 2; ++ks) {
      bf16x8 af[4], bfr[4];
#pragma unroll
      for (int t = 0; t < 4; ++t) {
        int r  = wm + t * 16 + (lane & 15);
        int kb = ks * 64 + ((lane >> 4) << 4);
        af[t]  = *(const bf16x8*)(As + r * 128 + SWB(r, kb));
        int rn = wn + t * 16 + (lane & 15);
        bfr[t] = *(const bf16x8*)(Bs + rn * 128 + SWB(rn, kb));
      }
#pragma unroll
      for (int mi = 0; mi < 4; ++mi)
#pragma unroll
        for (int ni = 0; ni < 4; ++ni)
          acc[mi][ni] = __builtin_amdgcn_mfma_f32_16x16x32_bf16(af[mi], bfr[ni], acc[mi][ni], 0, 0, 0);
    }
  }
  __syncthreads();
  if (n0 == 4352) {  // dt block: scalar softplus epilogue (only 32 valid cols)
#pragma unroll
    for (int mi = 0; mi < 4; ++mi) {
#pragma unroll
      for (int ni = 0; ni < 4; ++ni) {
        int r0 = m0 + wm + mi * 16 + ((lane >> 4) << 2);
        int c2 = n0 + wn + ni * 16 + (lane & 15);
        if (c2 < DINPROJ) {
          int h = c2 - 4352;
          float bias = dt_bias[h];
#pragma unroll
          for (int j = 0; j < 4; ++j) {
            float v = acc[mi][ni][j] + bias;
            dtb[(size_t)(r0 + j) * NHEADS + h] = (v > 20.f) ? v : log1pf(__expf(v));
          }
        }
      }
    }
  } else {
    // stage bf16 tile into LDS, then coalesced uint4 writes
#pragma unroll
    for (int mi = 0; mi < 4; ++mi)
#pragma unroll
      for (int ni = 0; ni < 4; ++ni) {
        int il = wm + mi * 16 + ((lane >> 4) << 2);
        int cl = wn + ni * 16 + (lane & 15);
#pragma unroll
        for (int j = 0; j < 4; ++j)
          *(u16*)((char*)sh + (il + j) * 256 + SWB(il + j, 2 * cl)) = f2bf(acc[mi][ni][j]);
      }
    __syncthreads();
    u16* dst; int ldst, n0c;
    if (n0 < 2048) { dst = zb;   ldst = DINNER;  n0c = n0; }
    else           { dst = xbcb; ldst = CONVDIM; n0c = n0 - 2048; }
#pragma unroll
    for (int s = 0; s < 8; ++s) {   // 128 rows x 16 uint4 = 2048 = 8*256
      int idx = s * 256 + tid;
      int r = idx >> 4, n16 = idx & 15;
      uint4 v = *(const uint4*)((char*)sh + r * 256 + SWB(r, n16 * 16));
      *(uint4*)(dst + (size_t)(m0 + r) * ldst + n0c + n16 * 8) = v;
    }
  }
}

// ---- GEMM2: out = yb @ Wout^T, f32 output ----
__global__ __launch_bounds__(256) void gemm_out(const u16* __restrict__ A,
                                                const u16* __restrict__ Bt,
                                                float* __restrict__ C) {
  const int K = DINNER, Nn = DMODEL;
  __shared__ u16 sh[32768];
  const int tid = threadIdx.x, lane = tid & 63, wave = tid >> 6;
  const int wm = (wave >> 1) << 6, wn = (wave & 1) << 6;
  // grid (8,64) -> 512 blocks, 64/XCD; panels of 4n x 8m (WS = 2MB+2MB)
  int flat = blockIdx.y * gridDim.x + blockIdx.x;
  int xcd = flat & 7, c = flat >> 3;          // c in [0,64)
  int p = c >> 5, r = c & 31;
  int n = p * 4 + (r & 3), dm = r >> 2;
  const int m0 = (xcd * 8 + dm) * 128;
  const int n0 = n * 128;

  f32x4 acc[4][4] = {};
  auto issue = [&](int buf, int k0) {
#pragma unroll
    for (int s = 0; s < 4; ++s) {
      int idx = s * 256 + tid;
      int row = idx >> 3, k16 = idx & 7;
      int swo = (k16 * 8) ^ ((row & 7) << 3);
      int lofs = (s * 256 + wave * 64) * 8;
      async_cp16(A + (size_t)(m0 + row) * K + k0 + swo, sh + buf * 16384 + lofs);
      async_cp16(Bt + (size_t)(n0 + row) * K + k0 + swo, sh + buf * 16384 + 8192 + lofs);
    }
  };
  issue(0, 0);
  const int nk = K / 64;
  for (int kt = 0; kt < nk; ++kt) {
    int buf = kt & 1;
    asm volatile("s_waitcnt vmcnt(0)" ::: "memory");
    __syncthreads();
    if (kt + 1 < nk) issue(buf ^ 1, (kt + 1) * 64);
    const char* As = (const char*)(sh + buf * 16384);
    const char* Bs = (const char*)(sh + buf * 16384 + 8192);
#pragma unroll
    for (int ks = 0; ks < 2; ++ks) {
      bf16x8 af[4], bfr[4];
#pragma unroll
      for (int t = 0; t < 4; ++t) {
        int r2 = wm + t * 16 + (lane & 15);
        int kb = ks * 64 + ((lane >> 4) << 4);
        af[t]  = *(const bf16x8*)(As + r2 * 128 + SWB(r2, kb));
        int rn = wn + t * 16 + (lane & 15);
        bfr[t] = *(const bf16x8*)(Bs + rn * 128 + SWB(rn, kb));
      }
#pragma unroll
      for (int mi = 0; mi < 4; ++mi)
#pragma unroll
        for (int ni = 0; ni < 4; ++ni)
          acc[mi][ni] = __builtin_amdgcn_mfma_f32_16x16x32_bf16(af[mi], bfr[ni], acc[mi][ni], 0, 0, 0);
    }
  }
#pragma unroll
  for (int mi = 0; mi < 4; ++mi) {
#pragma unroll
    for (int ni = 0; ni < 4; ++ni) {
      int r0 = m0 + wm + mi * 16 + ((lane >> 4) << 2);
      int c2 = n0 + wn + ni * 16 + (lane & 15);
#pragma unroll
      for (int j = 0; j < 4; ++j)
        C[(size_t)(r0 + j) * Nn + c2] = acc[mi][ni][j];
    }
  }
}

// -------- depthwise causal conv1d + bias + silu: 8 ch x 4 timesteps per thread --------
__global__ __launch_bounds__(256) void conv_silu(const u16* __restrict__ xbcb,
                                                 const float* __restrict__ cw,
                                                 const float* __restrict__ cb,
                                                 u16* __restrict__ convb) {
  int i = blockIdx.x * 256 + threadIdx.x;   // (BT_TOT/4) * 288 threads
  int bt4 = i / 288, c8 = i - bt4 * 288;
  int c0 = c8 * 8;
  int bt = bt4 * 4;                          // base output row (4 outputs: bt..bt+3)
  int t = bt & (SEQ - 1);

  float4 w[8];
  const float4* wp = (const float4*)(cw + (size_t)c0 * 4);
#pragma unroll
  for (int q = 0; q < 8; ++q) w[q] = wp[q];
  float4 b0 = ((const float4*)(cb + c0))[0];
  float4 b1 = ((const float4*)(cb + c0))[1];
  float bias[8] = {b0.x, b0.y, b0.z, b0.w, b1.x, b1.y, b1.z, b1.w};

  uint4 rows[7];
#pragma unroll
  for (int rix = 0; rix < 7; ++rix) {
    if (t - 3 + rix >= 0)
      rows[rix] = *(const uint4*)(xbcb + (size_t)(bt - 3 + rix) * CONVDIM + c0);
    else
      rows[rix] = make_uint4(0, 0, 0, 0);
  }

#pragma unroll
  for (int j = 0; j < 4; ++j) {
    float acc[8];
#pragma unroll
    for (int e = 0; e < 8; ++e) acc[e] = bias[e];
#pragma unroll
    for (int k = 0; k < 4; ++k) {
      const u16* e16 = (const u16*)&rows[j + k];
      float wk;
#pragma unroll
      for (int e = 0; e < 8; ++e) {
        wk = (k == 0) ? w[e].x : (k == 1) ? w[e].y : (k == 2) ? w[e].z : w[e].w;
        acc[e] = fmaf(bf2f(e16[e]), wk, acc[e]);
      }
    }
    uint4 o;
    u16* o16 = (u16*)&o;
#pragma unroll
    for (int e = 0; e < 8; ++e) {
      float s = acc[e] / (1.f + __expf(-acc[e]));
      o16[e] = f2bf(s);
    }
    *(uint4*)(convb + (size_t)(bt + j) * CONVDIM + c0) = o;
  }
}

// ---------------- per-(b,c,h) cumsum of dA over chunk; stores LOG2-domain ----------------
__global__ __launch_bounds__(128) void ssd_cumsum(const float* __restrict__ dtb,
                                                  const float* __restrict__ A_log,
                                                  float* __restrict__ dacs) {
  int bch = blockIdx.x;          // (b*32+c)*32+h
  int h = bch & 31, bc = bch >> 5;
  int q = threadIdx.x;
  float A = -__expf(A_log[h]);
  float v = dtb[((size_t)bc * 128 + q) * 32 + h] * A;
#pragma unroll
  for (int o = 1; o < 64; o <<= 1) {
    float u = __shfl_up(v, o, 64);
    if ((q & 63) >= o) v += u;
  }
  __shared__ float w0;
  if (q == 63) w0 = v;
  __syncthreads();
  if (q >= 64) v += w0;
  dacs[(size_t)bch * 128 + q] = v * LOG2E;
}

// ---------------- fused SSD intra per (b,c,h): G -> M -> Y_diag (+D*xh), S^T ----------------
__global__ __launch_bounds__(256) void ssd_intra2(const u16* __restrict__ convb,
                                                  const float* __restrict__ dacs,
                                                  const float* __restrict__ dtb,
                                                  const float* __restrict__ Dv,
                                                  u16* __restrict__ y,
                                                  u16* __restrict__ S) {
  __shared__ u16 Cc[128 * 128];
  __shared__ u16 Bb[128 * 128];
  __shared__ u16 xhT[64 * 128];
  int bch = (blockIdx.x & 7) * 256 + (blockIdx.x >> 3);  // XCD swizzle (2048 %8==0)
  int h = bch & 31, bc = bch >> 5;
  size_t row0 = (size_t)bc * 128;
  int tid = threadIdx.x, lane = tid & 63, wave = tid >> 6;
  const float* cs = dacs + (size_t)bch * 128;   // log2-domain cumsum

#pragma unroll
  for (int s = 0; s < 8; ++s) {
    int idx = s * 256 + tid;
    int r = idx >> 4, n16 = idx & 15;
    uint4 v = *(const uint4*)(convb + (row0 + r) * CONVDIM + (DINNER + DSTATE) + n16 * 8);
    *(uint4*)((char*)Cc + r * 256 + SWB(r, n16 * 16)) = v;
    uint4 w = *(const uint4*)(convb + (row0 + r) * CONVDIM + DINNER + n16 * 8);
    *(uint4*)((char*)Bb + r * 256 + SWB(r, n16 * 16)) = w;
  }
#pragma unroll
  for (int s = 0; s < 4; ++s) {
    int idx = s * 256 + tid;
    int q = idx >> 3, p0 = (idx & 7) * 8;
    uint4 v = *(const uint4*)(convb + (row0 + q) * CONVDIM + h * 64 + p0);
    const u16* e = (const u16*)&v;
#pragma unroll
    for (int k = 0; k < 8; ++k)
      *(u16*)((char*)xhT + (p0 + k) * 256 + SWB(p0 + k, 2 * q)) = e[k];
  }
  __syncthreads();

  // ---- G = C . B^T ----
  f32x4 g[2][8] = {};
#pragma unroll
  for (int ks = 0; ks < 4; ++ks) {
    int kb = ks * 64 + ((lane >> 4) << 4);
    bf16x8 a[2], b[8];
#pragma unroll
    for (int fi = 0; fi < 2; ++fi) {
      int r = 32 * wave + fi * 16 + (lane & 15);
      a[fi] = *(const bf16x8*)((const char*)Cc + r * 256 + SWB(r, kb));
    }
#pragma unroll
    for (int fj = 0; fj < 8; ++fj) {
      int rj = fj * 16 + (lane & 15);
      b[fj] = *(const bf16x8*)((const char*)Bb + rj * 256 + SWB(rj, kb));
    }
#pragma unroll
    for (int fi = 0; fi < 2; ++fi)
#pragma unroll
      for (int fj = 0; fj < 8; ++fj)
        g[fi][fj] = __builtin_amdgcn_mfma_f32_16x16x32_bf16(a[fi], b[fj], g[fi][fj], 0, 0, 0);
  }

  // ---- build M (bf16) into Cc rows owned by this wave ----
#pragma unroll
  for (int fi = 0; fi < 2; ++fi) {
    int ib = 32 * wave + fi * 16 + ((lane >> 4) << 2);
    float ci[4];
#pragma unroll
    for (int r = 0; r < 4; ++r) ci[r] = cs[ib + r];
#pragma unroll
    for (int fj = 0; fj < 8; ++fj) {
      int j = fj * 16 + (lane & 15);
      float cj = cs[j];
      float dj = dtb[(row0 + j) * NHEADS + h];
#pragma unroll
      for (int r = 0; r < 4; ++r) {
        int i = ib + r;
        float m = (j <= i) ? g[fi][fj][r] * exp2f(ci[r] - cj) * dj : 0.f;
        *(u16*)((char*)Cc + i * 256 + SWB(i, 2 * j)) = f2bf(m);
      }
    }
  }

  // ---- Y_diag = M . xh, triangular k-skip; + D*xh; store y (bf16) ----
  f32x4 yd[2][4] = {};
  for (int ks = 0; ks <= wave; ++ks) {
    int kb = ks * 64 + ((lane >> 4) << 4);
    bf16x8 a[2], b[4];
#pragma unroll
    for (int fi = 0; fi < 2; ++fi) {
      int r = 32 * wave + fi * 16 + (lane & 15);
      a[fi] = *(const bf16x8*)((const char*)Cc + r * 256 + SWB(r, kb));
    }
#pragma unroll
    for (int fp = 0; fp < 4; ++fp) {
      int pr = fp * 16 + (lane & 15);
      b[fp] = *(const bf16x8*)((const char*)xhT + pr * 256 + SWB(pr, kb));
    }
#pragma unroll
    for (int fi = 0; fi < 2; ++fi)
#pragma unroll
      for (int fp = 0; fp < 4; ++fp)
        yd[fi][fp] = __builtin_amdgcn_mfma_f32_16x16x32_bf16(a[fi], b[fp], yd[fi][fp], 0, 0, 0);
  }
  {
    float Dh = Dv[h];
#pragma unroll
    for (int fi = 0; fi < 2; ++fi) {
      int ib = 32 * wave + fi * 16 + ((lane >> 4) << 2);
#pragma unroll
      for (int fp = 0; fp < 4; ++fp) {
        int p = fp * 16 + (lane & 15);
#pragma unroll
        for (int r = 0; r < 4; ++r) {
          int i = ib + r;
          float xv = bf2f(*(const u16*)((const char*)xhT + p * 256 + SWB(p, 2 * i)));
          y[(row0 + i) * DINNER + h * 64 + p] = f2bf(yd[fi][fp][r] + Dh * xv);
        }
      }
    }
  }

  // ---- S[n][p] = sum_q (B[q][n]*w_q) * xh[q][p] ----
  float cl = cs[127];
  f32x4 sa[2][4] = {};
#pragma unroll
  for (int ks = 0; ks < 4; ++ks) {
    int qb = ks * 32 + ((lane >> 4) << 3);
    float wv[8];
#pragma unroll
    for (int e = 0; e < 8; ++e)
      wv[e] = exp2f(cl - cs[qb + e]) * dtb[(row0 + qb + e) * NHEADS + h];
    bf16x8 a[2], b[4];
#pragma unroll
    for (int fn = 0; fn < 2; ++fn) {
      int n = 32 * wave + fn * 16 + (lane & 15);
      bfpack t;
#pragma unroll
      for (int e = 0; e < 8; ++e) {
        int q = qb + e;
        float bv = bf2f(*(const u16*)((const char*)Bb + q * 256 + SWB(q, 2 * n)));
        t.u[e] = f2bf(bv * wv[e]);
      }
      a[fn] = t.v;
    }
    int kb = ks * 64 + ((lane >> 4) << 4);
#pragma unroll
    for (int fp = 0; fp < 4; ++fp) {
      int pr = fp * 16 + (lane & 15);
      b[fp] = *(const bf16x8*)((const char*)xhT + pr * 256 + SWB(pr, kb));
    }
#pragma unroll
    for (int fn = 0; fn < 2; ++fn)
#pragma unroll
      for (int fp = 0; fp < 4; ++fp)
        sa[fn][fp] = __builtin_amdgcn_mfma_f32_16x16x32_bf16(a[fn], b[fp], sa[fn][fp], 0, 0, 0);
  }
  __syncthreads();
#pragma unroll
  for (int fn = 0; fn < 2; ++fn) {
    int nb = 32 * wave + fn * 16 + ((lane >> 4) << 2);
#pragma unroll
    for (int fp = 0; fp < 4; ++fp) {
      int p = fp * 16 + (lane & 15);
#pragma unroll
      for (int r = 0; r < 4; ++r)
        *(u16*)((char*)Cc + p * 256 + SWB(p, 2 * (nb + r))) = f2bf(sa[fn][fp][r]);
    }
  }
  __syncthreads();
#pragma unroll
  for (int s = 0; s < 4; ++s) {
    int idx = s * 256 + tid;
    int p = idx >> 4, n16 = idx & 15;
    uint4 v = *(const uint4*)((char*)Cc + p * 256 + SWB(p, n16 * 16));
    *(uint4*)(S + (size_t)bch * 8192 + p * 128 + n16 * 8) = v;
  }
}

// ---------------- inter-chunk scan (in place; S layout [p][n] flat 8192/bch) -------
__global__ __launch_bounds__(256) void ssd_scan(u16* __restrict__ S,
                                                const float* __restrict__ dacs) {
  int f = blockIdx.x * 256 + threadIdx.x;   // 524288 total
  int e = f & 8191;
  int bh = f >> 13;
  int b = bh >> 5, h = bh & 31;
  float carry = 0.f;
  for (int c = 0; c < NCHUNK; ++c) {
    size_t bch = ((size_t)b * 32 + c) * 32 + h;
    size_t off = bch * 8192 + e;
    float s = bf2f(S[off]);
    S[off] = f2bf(carry);
    float cd = exp2f(dacs[bch * 128 + 127]);
    carry = fmaf(carry, cd, s);
  }
}

// ---------------- Y_off: y += exp2(cs_i) * C(128x128) . prev^T-layout (MFMA) ----------------
__global__ __launch_bounds__(256) void ssd_off2(const u16* __restrict__ convb,
                                                const u16* __restrict__ S,
                                                const float* __restrict__ dacs,
                                                u16* __restrict__ y) {
  __shared__ u16 Cc[128 * 128];
  __shared__ u16 pv[64 * 128];   // prev as [p][n]
  int bch = (blockIdx.x & 7) * 256 + (blockIdx.x >> 3);
  int h = bch & 31, bc = bch >> 5;
  size_t row0 = (size_t)bc * 128;
  int tid = threadIdx.x, lane = tid & 63, wave = tid >> 6;
  const float* cs = dacs + (size_t)bch * 128;

#pragma unroll
  for (int s = 0; s < 8; ++s) {
    int idx = s * 256 + tid;
    int r = idx >> 4, n16 = idx & 15;
    uint4 v = *(const uint4*)(convb + (row0 + r) * CONVDIM + (DINNER + DSTATE) + n16 * 8);
    *(uint4*)((char*)Cc + r * 256 + SWB(r, n16 * 16)) = v;
  }
#pragma unroll
  for (int s = 0; s < 4; ++s) {
    int idx = s * 256 + tid;
    int p = idx >> 4, n16 = idx & 15;
    uint4 v = *(const uint4*)(S + (size_t)bch * 8192 + p * 128 + n16 * 8);
    *(uint4*)((char*)pv + p * 256 + SWB(p, n16 * 16)) = v;
  }
  __syncthreads();

  f32x4 acc[2][4] = {};
#pragma unroll
  for (int ks = 0; ks < 4; ++ks) {
    int kb = ks * 64 + ((lane >> 4) << 4);
    bf16x8 a[2], b[4];
#pragma unroll
    for (int fi = 0; fi < 2; ++fi) {
      int r = 32 * wave + fi * 16 + (lane & 15);
      a[fi] = *(const bf16x8*)((const char*)Cc + r * 256 + SWB(r, kb));
    }
#pragma unroll
    for (int fp = 0; fp < 4; ++fp) {
      int pr = fp * 16 + (lane & 15);
      b[fp] = *(const bf16x8*)((const char*)pv + pr * 256 + SWB(pr, kb));
    }
#pragma unroll
    for (int fi = 0; fi < 2; ++fi)
#pragma unroll
      for (int fp = 0; fp < 4; ++fp)
        acc[fi][fp] = __builtin_amdgcn_mfma_f32_16x16x32_bf16(a[fi], b[fp], acc[fi][fp], 0, 0, 0);
  }
#pragma unroll
  for (int fi = 0; fi < 2; ++fi) {
    int ib = 32 * wave + fi * 16 + ((lane >> 4) << 2);
    float ei[4];
#pragma unroll
    for (int r = 0; r < 4; ++r) ei[r] = exp2f(cs[ib + r]);
#pragma unroll
    for (int fp = 0; fp < 4; ++fp) {
      int p = fp * 16 + (lane & 15);
#pragma unroll
      for (int r = 0; r < 4; ++r) {
        u16* yp = &y[(row0 + ib + r) * DINNER + h * 64 + p];
        float cur = bf2f(*yp);
        *yp = f2bf(fmaf(ei[r], acc[fi][fp][r], cur));
      }
    }
  }
}

// ---------------- gated RMSNorm -> bf16 ----------------
__global__ __launch_bounds__(256) void gated_norm(const u16* __restrict__ y,
                                                  const u16* __restrict__ zb,
                                                  const float* __restrict__ normw,
                                                  u16* __restrict__ yb) {
  size_t bt = blockIdx.x;
  int tid = threadIdx.x;
  const u16* yr = y + bt * DINNER;
  const u16* zr = zb + bt * DINNER;
  float g[8];
  float ss = 0.f;
#pragma unroll
  for (int s = 0; s < 8; ++s) {
    int c = tid + s * 256;
    float z = bf2f(zr[c]);
    float v = bf2f(yr[c]) * (z / (1.f + __expf(-z)));
    g[s] = v;
    ss = fmaf(v, v, ss);
  }
#pragma unroll
  for (int o = 1; o < 64; o <<= 1) ss += __shfl_xor(ss, o, 64);
  __shared__ float red[4];
  if ((tid & 63) == 0) red[tid >> 6] = ss;
  __syncthreads();
  float tot = red[0] + red[1] + red[2] + red[3];
  float r = rsqrtf(tot * (1.f / (float)DINNER) + 1e-5f);
#pragma unroll
  for (int s = 0; s < 8; ++s) {
    int c = tid + s * 256;
    yb[bt * DINNER + c] = f2bf(g[s] * r * normw[c]);
  }
}

// ---------------- workspace layout (~198 MiB) ----------------
constexpr size_t SZ_XB   = (size_t)BT_TOT * DMODEL * 2;
constexpr size_t SZ_WIB  = (size_t)DINPROJ * DMODEL * 2;
constexpr size_t SZ_WOB  = (size_t)DMODEL * DINNER * 2;
constexpr size_t SZ_ZB   = (size_t)BT_TOT * DINNER * 2;
constexpr size_t SZ_XBCB = (size_t)BT_TOT * CONVDIM * 2;   // reused by yb
constexpr size_t SZ_DTB  = (size_t)BT_TOT * NHEADS * 4;
constexpr size_t SZ_DACS = (size_t)2048 * 128 * 4;
constexpr size_t SZ_CONV = (size_t)BT_TOT * CONVDIM * 2;
constexpr size_t SZ_SB   = (size_t)2048 * 128 * 64 * 2;
constexpr size_t SZ_Y    = (size_t)BT_TOT * DINNER * 2;    // bf16

constexpr size_t OFF_XB   = 0;
constexpr size_t OFF_WIB  = OFF_XB + SZ_XB;
constexpr size_t OFF_WOB  = OFF_WIB + SZ_WIB;
constexpr size_t OFF_ZB   = OFF_WOB + SZ_WOB;
constexpr size_t OFF_XBCB = OFF_ZB + SZ_ZB;
constexpr size_t OFF_DTB  = OFF_XBCB + SZ_XBCB;
constexpr size_t OFF_DACS = OFF_DTB + SZ_DTB;
constexpr size_t OFF_CONV = OFF_DACS + SZ_DACS;
constexpr size_t OFF_SB   = OFF_CONV + SZ_CONV;
constexpr size_t OFF_Y    = OFF_SB + SZ_SB;
constexpr size_t WS_NEEDED = OFF_Y + SZ_Y;

extern "C" void kernel_launch(void* const* d_in, const int* in_sizes, int n_in,
                              void* d_out, int out_size, void* d_ws, size_t ws_size,
                              hipStream_t stream) {
  (void)in_sizes; (void)n_in; (void)out_size;
  if (ws_size < WS_NEEDED) return;

  const float* x      = (const float*)d_in[0];
  const float* Win    = (const float*)d_in[1];
  const float* cw     = (const float*)d_in[2];
  const float* cb     = (const float*)d_in[3];
  const float* dtbias = (const float*)d_in[4];
  const float* A_log  = (const float*)d_in[5];
  const float* Dv     = (const float*)d_in[6];
  const float* normw  = (const float*)d_in[7];
  const float* Wout   = (const float*)d_in[8];
  float* out = (float*)d_out;

  char* ws = (char*)d_ws;
  u16*   xb    = (u16*)  (ws + OFF_XB);
  u16*   wib   = (u16*)  (ws + OFF_WIB);
  u16*   wob   = (u16*)  (ws + OFF_WOB);
  u16*   zb    = (u16*)  (ws + OFF_ZB);
  u16*   xbcb  = (u16*)  (ws + OFF_XBCB);
  float* dtb   = (float*)(ws + OFF_DTB);
  float* dacs  = (float*)(ws + OFF_DACS);
  u16*   convb = (u16*)  (ws + OFF_CONV);
  u16*   sb    = (u16*)  (ws + OFF_SB);
  u16*   y     = (u16*)  (ws + OFF_Y);
  u16*   yb    = (u16*)  (ws + OFF_XBCB);  // overlay: xbcb dead after conv_silu

  cast_bf16<<<dim3(4096), dim3(256), 0, stream>>>(x, xb, BT_TOT * DMODEL / 8);
  tcast<<<dim3(DINPROJ / 32, DMODEL / 32), dim3(256), 0, stream>>>(Win, wib, DMODEL, DINPROJ);
  tcast<<<dim3(DMODEL / 32, DINNER / 32), dim3(256), 0, stream>>>(Wout, wob, DINNER, DMODEL);

  gemm_in<<<dim3(35, 64), dim3(256), 0, stream>>>(xb, wib, dtbias, zb, xbcb, dtb);

  conv_silu<<<dim3((BT_TOT / 4) * (CONVDIM / 8) / 256), dim3(256), 0, stream>>>(
      xbcb, cw, cb, convb);
  ssd_cumsum<<<dim3(2048), dim3(128), 0, stream>>>(dtb, A_log, dacs);
  ssd_intra2<<<dim3(2048), dim3(256), 0, stream>>>(convb, dacs, dtb, Dv, y, sb);
  ssd_scan<<<dim3(2048), dim3(256), 0, stream>>>(sb, dacs);
  ssd_off2<<<dim3(2048), dim3(256), 0, stream>>>(convb, sb, dacs, y);
  gated_norm<<<dim3(BT_TOT), dim3(256), 0, stream>>>(y, zb, normw, yb);

  gemm_out<<<dim3(8, 64), dim3(256), 0, stream>>>(yb, wob, out);
}